// Round 10
// baseline (653.874 us; speedup 1.0000x reference)
//
#include <hip/hip_runtime.h>
#include <cstddef>

#define HW 192
#define NP 36864          // H*W
#define CH 256
#define EDGES 294912
#define KSIG 289
#define SLOPE 0.01f
#define BNEPS 1e-5f
#define PADW 208          // padded image row (192 + 2*8)
#define PADSZ (PADW * PADW)   // 43264 u16 per channel
#define NP32 ((size_t)NP * 32)   // B-matrix K-slab stride (u16)

typedef unsigned short u16;
typedef __attribute__((ext_vector_type(8))) short bf16x8;
typedef __attribute__((ext_vector_type(4))) float f32x4;

__device__ __forceinline__ float leaky(float x) { return x >= 0.f ? x : SLOPE * x; }
__device__ __forceinline__ u16 f2bf(float x) {
  unsigned u = __float_as_uint(x);
  unsigned r = (u + 0x7fffu + ((u >> 16) & 1u)) >> 16;
  return (u16)r;
}
__device__ __forceinline__ float bf2f(unsigned h) { return __uint_as_float(h << 16); }
__device__ __forceinline__ void bnss(const float* sums, const float* sqs,
                                     const float* g, const float* b, int k,
                                     float& s, float& h) {
  float mean = sums[k] * (1.f / NP);
  float var = sqs[k] * (1.f / NP) - mean * mean;
  s = g[k] * rsqrtf(var + BNEPS);
  h = b[k] - mean * s;
}

// async global->LDS DMA: wave-uniform LDS base, per-lane global addr (lane*16B)
__device__ __forceinline__ void gload_lds16(const u16* g, u16* l) {
  __builtin_amdgcn_global_load_lds(
      (const __attribute__((address_space(1))) void*)g,
      (__attribute__((address_space(3))) void*)l, 16, 0, 0);
}

// ---- img = X^T (fp32 CxN) + padded leaky bf16 image (borders pre-zeroed) ------
__global__ __launch_bounds__(256) void k_transpose_pad(const float* __restrict__ src,
                                                       float* __restrict__ dst,
                                                       u16* __restrict__ pad) {
  __shared__ float tile[32][33];
  int s0 = blockIdx.x * 32, r0 = blockIdx.y * 32;   // s0 = channel, r0 = node
  int tx = threadIdx.x & 31, ty = threadIdx.x >> 5;
#pragma unroll
  for (int j = 0; j < 4; j++)
    tile[ty + 8 * j][tx] = src[(size_t)(r0 + ty + 8 * j) * CH + s0 + tx];
  __syncthreads();
  int n = r0 + tx;
  int y = n / HW, x = n - y * HW;
#pragma unroll
  for (int j = 0; j < 4; j++) {
    int c = s0 + ty + 8 * j;
    float v = tile[tx][ty + 8 * j];
    dst[(size_t)c * NP + n] = v;
    pad[(size_t)c * PADSZ + (y + 8) * PADW + x + 8] = f2bf(leaky(v));
  }
}

// ---- global Toeplitz build: Tg[c][ky][n][k] = w[c][ky][k-n] (bf16) ------------
__global__ __launch_bounds__(256) void k_mkT(const float* __restrict__ w,
                                             u16* __restrict__ Tg) {
  int c = blockIdx.x;
  const float* wc = w + c * 289;
  u16* tc = Tg + (size_t)c * 8704;
  for (int i = threadIdx.x; i < 8704; i += 256) {
    int ky = i >> 9, rem = i & 511, n = rem >> 5, k = rem & 31;
    int kx = k - n;
    float v = (kx >= 0 && kx < 17) ? wc[ky * 17 + kx] : 0.f;
    tc[i] = f2bf(v);
  }
}

// ---- weight fp32 -> bf16, K-SLAB TILED per matrix: (r,k) -> (k/32, r, k%32) ---
__global__ __launch_bounds__(256) void k_cvtW(const float* __restrict__ pw1,
                                              const float* __restrict__ f1w0,
                                              const float* __restrict__ f1w1,
                                              const float* __restrict__ dw1,
                                              const float* __restrict__ dw2,
                                              const float* __restrict__ f2w1,
                                              u16* __restrict__ out) {
  int i = blockIdx.x * 256 + threadIdx.x;   // 0..622591
  float v;
  int off, j, R, Klog;
  if (i < 65536)       { off = 0;      j = i;          v = pw1[j];  R = 256; Klog = 8; }
  else if (i < 131072) { off = 65536;  j = i - 65536;  v = f1w0[j]; R = 256; Klog = 8; }
  else if (i < 196608) { off = 131072; j = i - 131072; v = f1w1[j]; R = 256; Klog = 8; }
  else if (i < 262144) { off = 196608; j = i - 196608; v = dw1[j];  R = 256; Klog = 8; }
  else if (i < 360448) { off = 262144; j = i - 262144;
                         v = (j < KSIG * 256) ? dw2[j] : 0.f;       R = 384; Klog = 8; }
  else                 { off = 360448; j = i - 360448; v = f2w1[j]; R = 256; Klog = 10; }
  int r = j >> Klog, k = j & ((1 << Klog) - 1);
  int ni = off + (k >> 5) * (R * 32) + r * 32 + (k & 31);
  out[ni] = f2bf(v);
}

// ---------------- per-row stats, bf16 input (one block per row) ----------------
__global__ __launch_bounds__(256) void k_stats_bf(const u16* __restrict__ Xr,
                                                  float* __restrict__ sums,
                                                  float* __restrict__ sqs) {
  int row = blockIdx.x;
  int t = threadIdx.x;
  const uint4* p = (const uint4*)(Xr + (size_t)row * NP);
  float s = 0.f, q = 0.f;
  for (int i = t; i < NP / 8; i += 256) {
    uint4 v = p[i];
    unsigned w[4] = {v.x, v.y, v.z, v.w};
#pragma unroll
    for (int j = 0; j < 4; j++) {
      float a = bf2f(w[j] & 0xffffu), c = bf2f(w[j] >> 16);
      s += a + c; q += a * a + c * c;
    }
  }
  __shared__ float ss[256], qq[256];
  ss[t] = s; qq[t] = q;
  __syncthreads();
  for (int d = 128; d > 0; d >>= 1) {
    if (t < d) { ss[t] += ss[t + d]; qq[t] += qq[t + d]; }
    __syncthreads();
  }
  if (t == 0) { sums[row] = ss[0]; sqs[row] = qq[0]; }
}

// ---- reduce per-wave partials (1024 ch x 192 waves) -> sums/sqs ---------------
__global__ __launch_bounds__(256) void k_redstats(const float* __restrict__ ps,
                                                  const float* __restrict__ pq,
                                                  float* __restrict__ sums,
                                                  float* __restrict__ sqs) {
  int ch = blockIdx.x * 256 + threadIdx.x;
  const float* p1 = ps + (size_t)ch * 192;
  const float* p2 = pq + (size_t)ch * 192;
  float s = 0.f, q = 0.f;
  for (int i = 0; i < 192; i++) { s += p1[i]; q += p2[i]; }
  sums[ch] = s;
  sqs[ch] = q;
}

// ---- bf16 (M x NP) -> bf16 transposed K-SLAB tiled, leaky(bn(x)) inline -------
__global__ __launch_bounds__(256) void k_cvtT_bf(const u16* __restrict__ in,
                                                 u16* __restrict__ outT,
                                                 const float* __restrict__ sums,
                                                 const float* __restrict__ sqs,
                                                 const float* __restrict__ g,
                                                 const float* __restrict__ b, int M) {
  __shared__ float tile[32][65];
  int n0 = blockIdx.x * 64, k0 = blockIdx.y * 32;
  int t = threadIdx.x;
  int k = t >> 3, cg = (t & 7) * 8;
  float s, h; bnss(sums, sqs, g, b, k0 + k, s, h);
  uint4 v = *(const uint4*)&in[(size_t)(k0 + k) * NP + n0 + cg];
  unsigned w[4] = {v.x, v.y, v.z, v.w};
#pragma unroll
  for (int j = 0; j < 4; j++) {
    tile[k][cg + 2 * j]     = leaky(fmaf(bf2f(w[j] & 0xffffu), s, h));
    tile[k][cg + 2 * j + 1] = leaky(fmaf(bf2f(w[j] >> 16), s, h));
  }
  __syncthreads();
  int n = t >> 2, kg = (t & 3) * 8;
  uint4 o;
  o.x = (unsigned)f2bf(tile[kg + 0][n]) | ((unsigned)f2bf(tile[kg + 1][n]) << 16);
  o.y = (unsigned)f2bf(tile[kg + 2][n]) | ((unsigned)f2bf(tile[kg + 3][n]) << 16);
  o.z = (unsigned)f2bf(tile[kg + 4][n]) | ((unsigned)f2bf(tile[kg + 5][n]) << 16);
  o.w = (unsigned)f2bf(tile[kg + 6][n]) | ((unsigned)f2bf(tile[kg + 7][n]) << 16);
  *(uint4*)&outT[(size_t)(k0 >> 5) * NP32 + (size_t)(n0 + n) * 32 + kg] = o;
}

// ---- fuse1: img2 = img + bn(raw1); img2 fp32 (CxN) + leaky(img2)^T tiled ------
__global__ __launch_bounds__(256) void k_fuse1(const float* __restrict__ base,
                                               const u16* __restrict__ raw,
                                               const float* __restrict__ sums,
                                               const float* __restrict__ sqs,
                                               const float* __restrict__ g,
                                               const float* __restrict__ b,
                                               float* __restrict__ img2,
                                               u16* __restrict__ outT) {
  __shared__ float tile[32][65];
  int n0 = blockIdx.x * 64, k0 = blockIdx.y * 32;
  int t = threadIdx.x;
#pragma unroll
  for (int i = 0; i < 2; i++) {
    int ci = i * 256 + t;
    int k = ci >> 4, cg = (ci & 15) * 4;
    float s, h; bnss(sums, sqs, g, b, k0 + k, s, h);
    size_t idx = (size_t)(k0 + k) * NP + n0 + cg;
    float4 bv = *(const float4*)&base[idx];
    uint2 rv = *(const uint2*)&raw[idx];
    float r0 = bf2f(rv.x & 0xffffu), r1 = bf2f(rv.x >> 16);
    float r2 = bf2f(rv.y & 0xffffu), r3 = bf2f(rv.y >> 16);
    float4 o;
    o.x = bv.x + fmaf(r0, s, h); o.y = bv.y + fmaf(r1, s, h);
    o.z = bv.z + fmaf(r2, s, h); o.w = bv.w + fmaf(r3, s, h);
    *(float4*)&img2[idx] = o;
    tile[k][cg]     = leaky(o.x);
    tile[k][cg + 1] = leaky(o.y);
    tile[k][cg + 2] = leaky(o.z);
    tile[k][cg + 3] = leaky(o.w);
  }
  __syncthreads();
  int n = t >> 2, kg = (t & 3) * 8;
  uint4 o;
  o.x = (unsigned)f2bf(tile[kg + 0][n]) | ((unsigned)f2bf(tile[kg + 1][n]) << 16);
  o.y = (unsigned)f2bf(tile[kg + 2][n]) | ((unsigned)f2bf(tile[kg + 3][n]) << 16);
  o.z = (unsigned)f2bf(tile[kg + 4][n]) | ((unsigned)f2bf(tile[kg + 5][n]) << 16);
  o.w = (unsigned)f2bf(tile[kg + 6][n]) | ((unsigned)f2bf(tile[kg + 7][n]) << 16);
  *(uint4*)&outT[(size_t)(k0 >> 5) * NP32 + (size_t)(n0 + n) * 32 + kg] = o;
}

// ---- fuse2: Xn = img2 + bn(raw3); Xn fp32 NxC + Xn bf16 NxC (row) + tiled -----
__global__ __launch_bounds__(256) void k_fuse2(const float* __restrict__ base,
                                               const u16* __restrict__ raw,
                                               const float* __restrict__ sums,
                                               const float* __restrict__ sqs,
                                               const float* __restrict__ g,
                                               const float* __restrict__ b,
                                               float* __restrict__ XnT,
                                               u16* __restrict__ outT,
                                               u16* __restrict__ outTt) {
  __shared__ float tile[32][65];
  int n0 = blockIdx.x * 64, k0 = blockIdx.y * 32;
  int t = threadIdx.x;
#pragma unroll
  for (int i = 0; i < 2; i++) {
    int ci = i * 256 + t;
    int k = ci >> 4, cg = (ci & 15) * 4;
    float s, h; bnss(sums, sqs, g, b, k0 + k, s, h);
    size_t idx = (size_t)(k0 + k) * NP + n0 + cg;
    float4 bv = *(const float4*)&base[idx];
    uint2 rv = *(const uint2*)&raw[idx];
    float r0 = bf2f(rv.x & 0xffffu), r1 = bf2f(rv.x >> 16);
    float r2 = bf2f(rv.y & 0xffffu), r3 = bf2f(rv.y >> 16);
    tile[k][cg]     = bv.x + fmaf(r0, s, h);
    tile[k][cg + 1] = bv.y + fmaf(r1, s, h);
    tile[k][cg + 2] = bv.z + fmaf(r2, s, h);
    tile[k][cg + 3] = bv.w + fmaf(r3, s, h);
  }
  __syncthreads();
  int n = t >> 2, kg = (t & 3) * 8;
  float4 f0 = {tile[kg + 0][n], tile[kg + 1][n], tile[kg + 2][n], tile[kg + 3][n]};
  float4 f1 = {tile[kg + 4][n], tile[kg + 5][n], tile[kg + 6][n], tile[kg + 7][n]};
  *(float4*)&XnT[(size_t)(n0 + n) * CH + k0 + kg] = f0;
  *(float4*)&XnT[(size_t)(n0 + n) * CH + k0 + kg + 4] = f1;
  uint4 o;
  o.x = (unsigned)f2bf(f0.x) | ((unsigned)f2bf(f0.y) << 16);
  o.y = (unsigned)f2bf(f0.z) | ((unsigned)f2bf(f0.w) << 16);
  o.z = (unsigned)f2bf(f1.x) | ((unsigned)f2bf(f1.y) << 16);
  o.w = (unsigned)f2bf(f1.z) | ((unsigned)f2bf(f1.w) << 16);
  *(uint4*)&outT[(size_t)(n0 + n) * CH + k0 + kg] = o;                    // row (agg)
  *(uint4*)&outTt[(size_t)(k0 >> 5) * NP32 + (size_t)(n0 + n) * 32 + kg] = o; // tiled (GEMM)
}

// ---------------- MFMA GEMM (generic, M via blockIdx.y) ------------------------
// m97 structure: K-slab global + LINEAR stride-32 LDS + global_load_lds width=16.
__global__ __launch_bounds__(256) void k_mgemm(const u16* __restrict__ A,
                                               const u16* __restrict__ Bt,
                                               float* __restrict__ Outf,
                                               u16* __restrict__ Outb,
                                               const float* __restrict__ bias,
                                               int K, int Mstore, int actout,
                                               int aslab) {
  __shared__ u16 As[128 * 32];
  __shared__ u16 Bs[128 * 32];
  int t = threadIdx.x;
  int lane = t & 63, wave = t >> 6;
  int wm = (wave >> 1) * 64, wn = (wave & 1) * 64;
  int m0 = blockIdx.y * 128, n0 = blockIdx.x * 128;
  int r = lane & 15, q = lane >> 4;
  f32x4 acc[4][4];
#pragma unroll
  for (int a = 0; a < 4; a++)
#pragma unroll
    for (int b = 0; b < 4; b++) acc[a][b] = (f32x4){0.f, 0.f, 0.f, 0.f};

  int kiters = K >> 5;
  for (int ki = 0; ki < kiters; ki++) {
    const u16* Ag = A + (size_t)ki * aslab + (size_t)m0 * 32;
    const u16* Bg = Bt + (size_t)ki * NP32 + (size_t)n0 * 32;
#pragma unroll
    for (int j = 0; j < 4; j++) {
      int c = wave * 4 + j;          // 0..15, wave-uniform
      if (c < 8) gload_lds16(Ag + c * 512 + lane * 8, As + c * 512);
      else       gload_lds16(Bg + (c - 8) * 512 + lane * 8, Bs + (c - 8) * 512);
    }
    __syncthreads();                 // drains vmcnt -> LDS filled
    bf16x8 af[4], bfr[4];
#pragma unroll
    for (int mt = 0; mt < 4; mt++)
      af[mt] = *(const bf16x8*)&As[(wm + mt * 16 + r) * 32 + q * 8];
#pragma unroll
    for (int nt = 0; nt < 4; nt++)
      bfr[nt] = *(const bf16x8*)&Bs[(wn + nt * 16 + r) * 32 + q * 8];
#pragma unroll
    for (int mt = 0; mt < 4; mt++)
#pragma unroll
      for (int nt = 0; nt < 4; nt++)
        acc[mt][nt] = __builtin_amdgcn_mfma_f32_16x16x32_bf16(af[mt], bfr[nt], acc[mt][nt], 0, 0, 0);
    __syncthreads();                 // reads done before next overwrite
  }
#pragma unroll
  for (int mt = 0; mt < 4; mt++) {
    int mrow = m0 + wm + mt * 16 + q * 4;
#pragma unroll
    for (int i = 0; i < 4; i++) {
      int m = mrow + i;
      if (m >= Mstore) continue;
      float bs = bias ? bias[m] : 0.f;
#pragma unroll
      for (int nt = 0; nt < 4; nt++) {
        float v = acc[mt][nt][i] + bs;
        if (actout) v = leaky(v);
        size_t oi = (size_t)m * NP + n0 + wn + nt * 16 + r;
        if (Outb) Outb[oi] = f2bf(v); else Outf[oi] = v;
      }
    }
  }
}

// ---------------- MFMA GEMM, M=256, m97-style staging --------------------------
// r9-proven body. Optional OutbT: K-slab-tiled bf16 output (vectorized uint2
// stores). NO fused stats (r1/r8: per-row atomic reductions = poison).
__global__ __launch_bounds__(512) void k_mgemm256(const u16* __restrict__ A,
                                                  const u16* __restrict__ Bt,
                                                  float* __restrict__ Outf,
                                                  u16* __restrict__ Outb,
                                                  u16* __restrict__ OutbT,
                                                  const float* __restrict__ bias,
                                                  int K, int actout) {
  __shared__ u16 As[256 * 32];
  __shared__ u16 Bs[128 * 32];
  int t = threadIdx.x;
  int lane = t & 63, wave = t >> 6;
  int wm = (wave >> 1) * 64, wn = (wave & 1) * 64;   // wm 0..192, wn 0/64
  int n0 = blockIdx.x * 128;
  int r = lane & 15, q = lane >> 4;
  f32x4 acc[4][4];
#pragma unroll
  for (int a = 0; a < 4; a++)
#pragma unroll
    for (int b = 0; b < 4; b++) acc[a][b] = (f32x4){0.f, 0.f, 0.f, 0.f};

  int kiters = K >> 5;
  for (int ki = 0; ki < kiters; ki++) {
    const u16* Ag = A + (size_t)ki * 8192;                     // 256 rows * 32
    const u16* Bg = Bt + (size_t)ki * NP32 + (size_t)n0 * 32;
#pragma unroll
    for (int j = 0; j < 3; j++) {
      int c = wave * 3 + j;          // 0..23, wave-uniform
      if (c < 16) gload_lds16(Ag + c * 512 + lane * 8, As + c * 512);
      else        gload_lds16(Bg + (c - 16) * 512 + lane * 8, Bs + (c - 16) * 512);
    }
    __syncthreads();                 // drains vmcnt -> LDS filled
    bf16x8 af[4], bfr[4];
#pragma unroll
    for (int mt = 0; mt < 4; mt++)
      af[mt] = *(const bf16x8*)&As[(wm + mt * 16 + r) * 32 + q * 8];
#pragma unroll
    for (int nt = 0; nt < 4; nt++)
      bfr[nt] = *(const bf16x8*)&Bs[(wn + nt * 16 + r) * 32 + q * 8];
#pragma unroll
    for (int mt = 0; mt < 4; mt++)
#pragma unroll
      for (int nt = 0; nt < 4; nt++)
        acc[mt][nt] = __builtin_amdgcn_mfma_f32_16x16x32_bf16(af[mt], bfr[nt], acc[mt][nt], 0, 0, 0);
    __syncthreads();                 // reads done before next overwrite
  }
#pragma unroll
  for (int mt = 0; mt < 4; mt++) {
    int mrow = wm + mt * 16 + q * 4;
    if (OutbT) {
      int slab = (wm + mt * 16) >> 5;           // m-slab index
      int ko = (mt & 1) * 16 + q * 4;           // (m & 31) base for i=0
      float b0 = bias ? bias[mrow + 0] : 0.f;
      float b1 = bias ? bias[mrow + 1] : 0.f;
      float b2 = bias ? bias[mrow + 2] : 0.f;
      float b3 = bias ? bias[mrow + 3] : 0.f;
#pragma unroll
      for (int nt = 0; nt < 4; nt++) {
        int n = n0 + wn + nt * 16 + r;
        float w0 = acc[mt][nt][0] + b0, w1 = acc[mt][nt][1] + b1;
        float w2 = acc[mt][nt][2] + b2, w3 = acc[mt][nt][3] + b3;
        if (actout) { w0 = leaky(w0); w1 = leaky(w1); w2 = leaky(w2); w3 = leaky(w3); }
        uint2 pk;
        pk.x = (unsigned)f2bf(w0) | ((unsigned)f2bf(w1) << 16);
        pk.y = (unsigned)f2bf(w2) | ((unsigned)f2bf(w3) << 16);
        *(uint2*)&OutbT[(size_t)slab * NP32 + (size_t)n * 32 + ko] = pk;
      }
      continue;
    }
#pragma unroll
    for (int i = 0; i < 4; i++) {
      int m = mrow + i;
      float bs = bias ? bias[m] : 0.f;
#pragma unroll
      for (int nt = 0; nt < 4; nt++) {
        float v = acc[mt][nt][i] + bs;
        if (actout) v = leaky(v);
        size_t oi = (size_t)m * NP + n0 + wn + nt * 16 + r;
        if (Outb) Outb[oi] = f2bf(v); else Outf[oi] = v;
      }
    }
  }
}

// ---------------- depthwise 17x17 conv via MFMA, padded bf16 input -------------
__global__ __launch_bounds__(256) void k_dwconv17(const u16* __restrict__ pad,
                                                  const u16* __restrict__ Tg,
                                                  u16* __restrict__ outb) {
  int c = blockIdx.y;
  int tile = blockIdx.x;                  // 0..8
  int ty0 = (tile / 3) * 64, tx0 = (tile % 3) * 64;
  __shared__ u16 smIn[80 * 88];
  __shared__ u16 smT[17 * 16 * 40];
  const u16* pc = pad + (size_t)c * PADSZ;
  for (int cc = threadIdx.x; cc < 800; cc += 256) {
    int rr = cc / 10, j = cc - rr * 10;
    uint4 v = *(const uint4*)(pc + (ty0 + rr) * PADW + tx0 + j * 8);
    *(uint4*)(smIn + rr * 88 + j * 8) = v;
  }
  const u16* tc = Tg + (size_t)c * 8704;
  for (int cc = threadIdx.x; cc < 1088; cc += 256) {
    int rr = cc >> 2, j = cc & 3;
    uint4 v = *(const uint4*)(tc + rr * 32 + j * 8);
    *(uint4*)(smT + rr * 40 + j * 8) = v;
  }
  __syncthreads();
  int lane = threadIdx.x & 63, wave = threadIdx.x >> 6;
  int wy = wave * 16;
  int r = lane & 15, q = lane >> 4;
  f32x4 acc[4];
#pragma unroll
  for (int xt = 0; xt < 4; xt++) acc[xt] = (f32x4){0.f, 0.f, 0.f, 0.f};
#pragma unroll
  for (int ky = 0; ky < 17; ky++) {
    bf16x8 bfrag = *(const bf16x8*)&smT[(ky * 16 + r) * 40 + q * 8];
    int rowA = wy + r + ky;
#pragma unroll
    for (int xt = 0; xt < 4; xt++) {
      bf16x8 afrag = *(const bf16x8*)&smIn[rowA * 88 + xt * 16 + q * 8];
      acc[xt] = __builtin_amdgcn_mfma_f32_16x16x32_bf16(afrag, bfrag, acc[xt], 0, 0, 0);
    }
  }
  u16* oc = outb + (size_t)c * NP;
#pragma unroll
  for (int xt = 0; xt < 4; xt++) {
    int x = tx0 + xt * 16 + r;
#pragma unroll
    for (int i = 0; i < 4; i++) {
      int y = ty0 + wy + q * 4 + i;
      oc[y * HW + x] = f2bf(acc[xt][i]);
    }
  }
}

// ---------------- grouped 3x3 conv, row-sliding, no LDS, no barrier ------------
// Fused per-wave BN partials: after the stores, each wave (one row, 4 channels)
// shfl-reduces sum/sumsq and lane 0 writes ONE partial to a UNIQUE address
// (plain stores, no atomics - the r1/r8 poison was atomic contention).
__global__ __launch_bounds__(256) void k_conv3x4(const float* __restrict__ in,
                                                 const float* __restrict__ w,
                                                 u16* __restrict__ out,
                                                 float* __restrict__ psum,
                                                 float* __restrict__ psq) {
  int wave = threadIdx.x >> 6, lane = threadIdx.x & 63;
  int c = blockIdx.y;
  int y = blockIdx.x * 4 + wave;
  const float* wc = w + (size_t)(4 * c) * 9;
  float wr[36];
#pragma unroll
  for (int k = 0; k < 36; k++) wr[k] = wc[k];
  float acc[4][3];
#pragma unroll
  for (int oc = 0; oc < 4; oc++)
#pragma unroll
    for (int s = 0; s < 3; s++) acc[oc][s] = 0.f;
  const float* base = in + (size_t)c * NP;
#pragma unroll
  for (int ky = 0; ky < 3; ky++) {
    int ry = y + ky - 1;
    if (ry < 0 || ry >= HW) continue;
    const float* rp = base + ry * HW;
    float a0 = leaky(rp[lane]);
    float a1 = leaky(rp[64 + lane]);
    float a2 = leaky(rp[128 + lane]);
    float e0 = __shfl(a0, 63), e1 = __shfl(a1, 63);
    float b1 = __shfl(a1, 0),  b2 = __shfl(a2, 0);
    float l0 = __shfl_up(a0, 1); if (lane == 0) l0 = 0.f;
    float l1 = __shfl_up(a1, 1); if (lane == 0) l1 = e0;
    float l2 = __shfl_up(a2, 1); if (lane == 0) l2 = e1;
    float r0 = __shfl_down(a0, 1); if (lane == 63) r0 = b1;
    float r1 = __shfl_down(a1, 1); if (lane == 63) r1 = b2;
    float r2 = __shfl_down(a2, 1); if (lane == 63) r2 = 0.f;
#pragma unroll
    for (int oc = 0; oc < 4; oc++) {
      float w0 = wr[oc * 9 + ky * 3], w1 = wr[oc * 9 + ky * 3 + 1], w2 = wr[oc * 9 + ky * 3 + 2];
      acc[oc][0] = fmaf(w0, l0, fmaf(w1, a0, fmaf(w2, r0, acc[oc][0])));
      acc[oc][1] = fmaf(w0, l1, fmaf(w1, a1, fmaf(w2, r1, acc[oc][1])));
      acc[oc][2] = fmaf(w0, l2, fmaf(w1, a2, fmaf(w2, r2, acc[oc][2])));
    }
  }
  size_t ob = (size_t)(4 * c) * NP + (size_t)y * HW + lane;
#pragma unroll
  for (int oc = 0; oc < 4; oc++) {
    out[ob + (size_t)oc * NP]       = f2bf(acc[oc][0]);
    out[ob + (size_t)oc * NP + 64]  = f2bf(acc[oc][1]);
    out[ob + (size_t)oc * NP + 128] = f2bf(acc[oc][2]);
  }
  // per-wave stats partials (wr[] dead here; only acc live)
#pragma unroll
  for (int oc = 0; oc < 4; oc++) {
    float rs = acc[oc][0] + acc[oc][1] + acc[oc][2];
    float rq = acc[oc][0] * acc[oc][0] + acc[oc][1] * acc[oc][1] + acc[oc][2] * acc[oc][2];
#pragma unroll
    for (int d = 1; d < 64; d <<= 1) { rs += __shfl_xor(rs, d); rq += __shfl_xor(rq, d); }
    if (lane == 0) {
      size_t pi = (size_t)(4 * c + oc) * 192 + y;
      psum[pi] = rs;
      psq[pi]  = rq;
    }
  }
}

// ---------------- edge scores + dst histogram ----------------------------------
__global__ __launch_bounds__(256) void k_edge(const int* __restrict__ info,
                                              const float* __restrict__ msk,
                                              const float* __restrict__ sig,
                                              float* __restrict__ aij,
                                              int* __restrict__ counts) {
  int e = blockIdx.x * 256 + threadIdx.x;
  int4 ii = ((const int4*)info)[e];
  float s = sig[(size_t)ii.y * NP + ii.x] + sig[(size_t)ii.w * NP + ii.z];
  s = fminf(fmaxf(s, -5.f), 5.f);
  aij[e] = expf(s) * msk[e];
  atomicAdd(&counts[ii.z], 1);
}

// ---------------- counting-sort by dst -----------------------------------------
__global__ __launch_bounds__(256) void k_scan1(const int* __restrict__ counts,
                                               int* __restrict__ offsets,
                                               int* __restrict__ bsum) {
  __shared__ int sm[256];
  int t = threadIdx.x;
  int i = blockIdx.x * 256 + t;
  int v = counts[i];
  sm[t] = v;
  __syncthreads();
  for (int d = 1; d < 256; d <<= 1) {
    int add = (t >= d) ? sm[t - d] : 0;
    __syncthreads();
    sm[t] += add;
    __syncthreads();
  }
  offsets[i] = sm[t] - v;
  if (t == 255) bsum[blockIdx.x] = sm[255];
}
__global__ __launch_bounds__(256) void k_scan2(const int* __restrict__ bsum,
                                               int* __restrict__ boff) {
  __shared__ int sm[256];
  int t = threadIdx.x;
  int v = (t < 144) ? bsum[t] : 0;
  sm[t] = v;
  __syncthreads();
  for (int d = 1; d < 256; d <<= 1) {
    int add = (t >= d) ? sm[t - d] : 0;
    __syncthreads();
    sm[t] += add;
    __syncthreads();
  }
  boff[t] = sm[t] - v;
}
__global__ __launch_bounds__(256) void k_scan3(int* __restrict__ offsets,
                                               const int* __restrict__ boff,
                                               int* __restrict__ cursor) {
  int i = blockIdx.x * 256 + threadIdx.x;
  int o = offsets[i] + boff[blockIdx.x];
  offsets[i] = o;
  cursor[i] = o;
  if (i == 0) offsets[NP] = EDGES;
}
// scatter (src, aij) pre-sorted by dst
__global__ __launch_bounds__(256) void k_scatter(const int* __restrict__ info,
                                                 const float* __restrict__ aij,
                                                 int* __restrict__ cursor,
                                                 int* __restrict__ srcs,
                                                 float* __restrict__ aijw) {
  int e = blockIdx.x * 256 + threadIdx.x;
  int4 ii = ((const int4*)info)[e];
  int pos = atomicAdd(&cursor[ii.z], 1);
  srcs[pos] = ii.x;
  aijw[pos] = aij[e];
}

// ---------------- per-node aggregation: half-wave per edge stream --------------
__global__ __launch_bounds__(256) void k_agg(const int* __restrict__ offsets,
                                             const int* __restrict__ srcs,
                                             const float* __restrict__ aijw,
                                             const u16* __restrict__ XnBf,
                                             u16* __restrict__ XtrBf) {
  int wave = threadIdx.x >> 6, lane = threadIdx.x & 63;
  int node = blockIdx.x * 4 + wave;
  int o0 = offsets[node], o1 = offsets[node + 1];
  int half = lane >> 5, l32 = lane & 31;
  float acc[8] = {0.f, 0.f, 0.f, 0.f, 0.f, 0.f, 0.f, 0.f};
  float asum = 0.f;
  int i = o0 + half;
  for (; i + 2 < o1; i += 4) {
    int s0 = srcs[i], s1 = srcs[i + 2];
    float a0 = aijw[i], a1 = aijw[i + 2];
    uint4 v0 = ((const uint4*)(XnBf + (size_t)s0 * CH))[l32];
    uint4 v1 = ((const uint4*)(XnBf + (size_t)s1 * CH))[l32];
    unsigned w0[4] = {v0.x, v0.y, v0.z, v0.w};
    unsigned w1[4] = {v1.x, v1.y, v1.z, v1.w};
#pragma unroll
    for (int j = 0; j < 4; j++) {
      acc[2 * j]     = fmaf(a0, bf2f(w0[j] & 0xffffu), acc[2 * j]);
      acc[2 * j + 1] = fmaf(a0, bf2f(w0[j] >> 16),     acc[2 * j + 1]);
      acc[2 * j]     = fmaf(a1, bf2f(w1[j] & 0xffffu), acc[2 * j]);
      acc[2 * j + 1] = fmaf(a1, bf2f(w1[j] >> 16),     acc[2 * j + 1]);
    }
    asum += a0 + a1;
  }
  for (; i < o1; i += 2) {
    int s = srcs[i];
    float a = aijw[i];
    uint4 v = ((const uint4*)(XnBf + (size_t)s * CH))[l32];
    unsigned w[4] = {v.x, v.y, v.z, v.w};
#pragma unroll
    for (int j = 0; j < 4; j++) {
      acc[2 * j]     = fmaf(a, bf2f(w[j] & 0xffffu), acc[2 * j]);
      acc[2 * j + 1] = fmaf(a, bf2f(w[j] >> 16),     acc[2 * j + 1]);
    }
    asum += a;
  }
#pragma unroll
  for (int j = 0; j < 8; j++) acc[j] += __shfl_xor(acc[j], 32, 64);
  asum += __shfl_xor(asum, 32, 64);
  if (half == 0) {
    float inv = 1.f / (asum + 1e-5f);
    uint4 o;
    o.x = (unsigned)f2bf(acc[0] * inv) | ((unsigned)f2bf(acc[1] * inv) << 16);
    o.y = (unsigned)f2bf(acc[2] * inv) | ((unsigned)f2bf(acc[3] * inv) << 16);
    o.z = (unsigned)f2bf(acc[4] * inv) | ((unsigned)f2bf(acc[5] * inv) << 16);
    o.w = (unsigned)f2bf(acc[6] * inv) | ((unsigned)f2bf(acc[7] * inv) << 16);
    ((uint4*)(XtrBf + (size_t)node * CH))[l32] = o;
  }
}

// ---------------- bn1d stats (bf16 input) --------------------------------------
__global__ __launch_bounds__(256) void k_colstats(const u16* __restrict__ Xt,
                                                  float* __restrict__ sums,
                                                  float* __restrict__ sqs) {
  int c = threadIdx.x;
  float s = 0.f, q = 0.f;
  for (int n = blockIdx.x; n < NP; n += gridDim.x) {
    float v = bf2f(Xt[(size_t)n * CH + c]);
    s += v; q += v * v;
  }
  atomicAdd(&sums[c], s);
  atomicAdd(&sqs[c], q);
}

// ---------------- img4 = transpose(Xn + bn1d(Xtr bf16))  (N x C -> C x N) ------
__global__ __launch_bounds__(256) void k_mkimg4(const float* __restrict__ Xn,
                                                const u16* __restrict__ XtrBf,
                                                const float* __restrict__ sums,
                                                const float* __restrict__ sqs,
                                                const float* __restrict__ g,
                                                const float* __restrict__ b,
                                                float* __restrict__ img4) {
  __shared__ float tile[32][33];
  int c0 = blockIdx.x * 32, n0 = blockIdx.y * 32;
  int tx = threadIdx.x & 31, ty = threadIdx.x >> 5;
  int c = c0 + tx;
  float s, h; bnss(sums, sqs, g, b, c, s, h);
#pragma unroll
  for (int j = 0; j < 4; j++) {
    size_t idx = (size_t)(n0 + ty + 8 * j) * CH + c;
    tile[ty + 8 * j][tx] = Xn[idx] + fmaf(bf2f(XtrBf[idx]), s, h);
  }
  __syncthreads();
#pragma unroll
  for (int j = 0; j < 4; j++) {
    int cc = c0 + ty + 8 * j;
    img4[(size_t)cc * NP + n0 + tx] = tile[tx][ty + 8 * j];
  }
}

// ---------------- out(N x C) = transpose(bn(raw5 bf16) + img4) -----------------
__global__ __launch_bounds__(256) void k_final(const u16* __restrict__ raw5,
                                               const float* __restrict__ img4,
                                               const float* __restrict__ sums,
                                               const float* __restrict__ sqs,
                                               const float* __restrict__ g,
                                               const float* __restrict__ b,
                                               float* __restrict__ out) {
  __shared__ float tile[32][33];
  int n0 = blockIdx.x * 32, c0 = blockIdx.y * 32;
  int tx = threadIdx.x & 31, ty = threadIdx.x >> 5;
#pragma unroll
  for (int j = 0; j < 4; j++) {
    int c = c0 + ty + 8 * j;
    float s, h; bnss(sums, sqs, g, b, c, s, h);
    size_t idx = (size_t)c * NP + n0 + tx;
    tile[ty + 8 * j][tx] = fmaf(bf2f(raw5[idx]), s, h) + img4[idx];
  }
  __syncthreads();
#pragma unroll
  for (int j = 0; j < 4; j++) {
    int n = n0 + ty + 8 * j;
    out[(size_t)n * CH + c0 + tx] = tile[tx][ty + 8 * j];
  }
}

extern "C" void kernel_launch(void* const* d_in, const int* in_sizes, int n_in,
                              void* d_out, int out_size, void* d_ws, size_t ws_size,
                              hipStream_t stream) {
  (void)in_sizes; (void)n_in; (void)out_size; (void)ws_size;
  const float* X    = (const float*)d_in[0];
  const int*   info = (const int*)d_in[1];
  const float* msk  = (const float*)d_in[2];
  const float* pw0  = (const float*)d_in[3];
  const float* pg0  = (const float*)d_in[4];
  const float* pb0  = (const float*)d_in[5];
  const float* pw1  = (const float*)d_in[6];
  const float* pg1  = (const float*)d_in[7];
  const float* pb1  = (const float*)d_in[8];
  const float* f1w0 = (const float*)d_in[9];
  const float* f1g0 = (const float*)d_in[10];
  const float* f1b0 = (const float*)d_in[11];
  const float* f1w1 = (const float*)d_in[12];
  const float* f1g1 = (const float*)d_in[13];
  const float* f1b1 = (const float*)d_in[14];
  const float* dw1  = (const float*)d_in[15];
  const float* db1  = (const float*)d_in[16];
  const float* dw2  = (const float*)d_in[17];
  const float* db2  = (const float*)d_in[18];
  const float* bng  = (const float*)d_in[19];
  const float* bnb  = (const float*)d_in[20];
  const float* f2w0 = (const float*)d_in[21];
  const float* f2g0 = (const float*)d_in[22];
  const float* f2b0 = (const float*)d_in[23];
  const float* f2w1 = (const float*)d_in[24];
  const float* f2g1 = (const float*)d_in[25];
  const float* f2b1 = (const float*)d_in[26];
  float* out = (float*)d_out;

  float* ws = (float*)d_ws;
  float* sum0 = ws + 0;    float* sq0 = ws + 256;
  float* sum1 = ws + 512;  float* sq1 = ws + 768;
  float* sum2 = ws + 1024; float* sq2 = ws + 1280;
  float* sum3 = ws + 1536; float* sq3 = ws + 1792;
  float* sum5 = ws + 2048; float* sq5 = ws + 2304;
  float* sumT = ws + 2560; float* sqT = ws + 2816;   // atomic targets, zeroed
  float* sum4 = ws + 3072; float* sq4 = ws + 4096;   // 1024 each
  int* counts  = (int*)(ws + 8192);
  int* offsets = (int*)(ws + 45056);
  int* cursor  = (int*)(ws + 82176);
  int* bsum    = (int*)(ws + 119296);
  int* boff    = (int*)(ws + 119552);
  int* srcs    = (int*)(ws + 131072);      // EDGES
  float* aij   = ws + 425984;              // EDGES (unsorted)
  const size_t S = (size_t)NP * CH;        // 9437184 words
  float* slotD = ws + 720896;
  float* slotB = slotD + S;
  float* slotA = slotB + S;
  float* slotC = slotA + S;
  u16* bfB  = (u16*)(slotC + S);           // NP x 256 bf16
  u16* bfH  = bfB + S;                     // raw0/raw1/raw2/raw3/h-bf16
  float* sigT = (float*)(bfH + S);         // KSIG x NP fp32
  u16* bfW  = (u16*)(sigT + (size_t)KSIG * NP);
  float* aijw = (float*)(bfW + 622592);    // EDGES, sorted by dst
  // early-phase aliases into dead fp32 slots:
  u16* Ppad = (u16*)slotC;                 // 256ch x 208x208 bf16 padded leaky img
  u16* Tg   = (u16*)slotD;                 // 256 x 8704 Toeplitz
  u16* raw4bf  = (u16*)slotB;              // 1024 x NP bf16, spans slotB+slotA
  u16* bfT1024 = bfB;                      // NP x 1024 bf16 (K-slab tiled)
  u16* XtrBf   = (u16*)slotD;              // N x C bf16 (img2/Tg dead)
  u16* raw5bf  = (u16*)slotB;              // C x NP bf16 (raw4bf dead after cvtT_bf)
  u16* bfBt    = (u16*)sigT;               // NP x 256 bf16 K-slab tiled (dis GEMM B);
                                           // dead before k_mgemm writes sigT
  float* psum4 = slotD;                    // conv3x4 stats partials (1024 x 192);
  float* psq4  = slotD + 196608;           // XtrBf dead after k_mkimg4

  hipMemsetAsync(ws, 0, 5120 * sizeof(float), stream);
  hipMemsetAsync(counts, 0, NP * sizeof(int), stream);
  hipMemsetAsync(Ppad, 0, (size_t)PADSZ * CH * sizeof(u16), stream);

  dim3 b256(256), b512(512);
  k_cvtW<<<2432, b256, 0, stream>>>(pw1, f1w0, f1w1, dw1, dw2, f2w1, bfW);
  k_mkT<<<CH, b256, 0, stream>>>(pw0, Tg);
  // img = X^T -> slotA ; padded leaky bf16 -> Ppad
  k_transpose_pad<<<dim3(CH / 32, NP / 32), b256, 0, stream>>>(X, slotA, Ppad);
  // ppm depthwise -> raw0 bf16 (bfH)
  k_dwconv17<<<dim3(9, CH), b256, 0, stream>>>(Ppad, Tg, bfH);
  k_stats_bf<<<CH, b256, 0, stream>>>(bfH, sum0, sq0);
  k_cvtT_bf<<<dim3(NP / 64, 8), b256, 0, stream>>>(bfH, bfB, sum0, sq0, pg0, pb0, CH);
  // ppm 1x1 -> raw1 bf16 (bfH; raw0 dead)
  k_mgemm256<<<NP / 128, b512, 0, stream>>>(bfW, bfB, nullptr, bfH, nullptr, nullptr, CH, 0);
  k_stats_bf<<<CH, b256, 0, stream>>>(bfH, sum1, sq1);
  // img2 = img + bn(raw1) -> slotD (Tg dead) ; bfB = leaky(img2)^T tiled
  k_fuse1<<<dim3(NP / 64, 8), b256, 0, stream>>>(slotA, bfH, sum1, sq1, pg1, pb1, slotD, bfB);
  // ffn1 conv0 -> raw2 bf16 (bfH)
  k_mgemm256<<<NP / 128, b512, 0, stream>>>(bfW + 65536, bfB, nullptr, bfH, nullptr, nullptr, CH, 0);
  k_stats_bf<<<CH, b256, 0, stream>>>(bfH, sum2, sq2);
  k_cvtT_bf<<<dim3(NP / 64, 8), b256, 0, stream>>>(bfH, bfB, sum2, sq2, f1g0, f1b0, CH);
  // ffn1 conv1 -> raw3 bf16 (bfH)
  k_mgemm256<<<NP / 128, b512, 0, stream>>>(bfW + 131072, bfB, nullptr, bfH, nullptr, nullptr, CH, 0);
  k_stats_bf<<<CH, b256, 0, stream>>>(bfH, sum3, sq3);
  // Xn = img2 + bn(raw3): fp32 NxC -> slotA ; bf16 NxC row -> bfB ; tiled -> bfBt
  k_fuse2<<<dim3(NP / 64, 8), b256, 0, stream>>>(slotD, bfH, sum3, sq3, f1g1, f1b1, slotA, bfB, bfBt);
  // dis: h -> bfH DIRECTLY in K-slab tiled bf16, bias+leaky, uint2 tiled stores
  k_mgemm256<<<NP / 128, b512, 0, stream>>>(bfW + 196608, bfBt, nullptr, nullptr, bfH, db1, CH, 1);
  k_mgemm<<<dim3(NP / 128, 3), b256, 0, stream>>>(bfW + 262144, bfH, sigT, nullptr, db2, CH, KSIG, 0, 12288);
  // edges
  k_edge<<<EDGES / 256, b256, 0, stream>>>(info, msk, sigT, aij, counts);
  k_scan1<<<NP / 256, b256, 0, stream>>>(counts, offsets, bsum);
  k_scan2<<<1, b256, 0, stream>>>(bsum, boff);
  k_scan3<<<NP / 256, b256, 0, stream>>>(offsets, boff, cursor);
  k_scatter<<<EDGES / 256, b256, 0, stream>>>(info, aij, cursor, srcs, aijw);
  // Xtr bf16 -> XtrBf (slotD; img2 dead)  [bfB row-major]
  k_agg<<<NP / 4, b256, 0, stream>>>(offsets, srcs, aijw, bfB, XtrBf);
  k_colstats<<<288, b256, 0, stream>>>(XtrBf, sumT, sqT);
  // img4 -> slotC (Ppad dead)
  k_mkimg4<<<dim3(CH / 32, NP / 32), b256, 0, stream>>>(slotA, XtrBf, sumT, sqT, bng, bnb, slotC);
  // ffn2 grouped 3x3 -> raw4bf (slotB+slotA; Xn fp32 dead) + stats partials
  // (slotD free: XtrBf consumed by mkimg4)
  k_conv3x4<<<dim3(48, CH), b256, 0, stream>>>(slotC, f2w0, raw4bf, psum4, psq4);
  k_redstats<<<4, b256, 0, stream>>>(psum4, psq4, sum4, sq4);
  k_cvtT_bf<<<dim3(NP / 64, 32), b256, 0, stream>>>(raw4bf, bfT1024, sum4, sq4, f2g0, f2b0, 1024);
  // ffn2 1x1 -> raw5 bf16 (slotB; raw4bf consumed)
  k_mgemm256<<<NP / 128, b512, 0, stream>>>(bfW + 360448, bfT1024, nullptr, raw5bf, nullptr, nullptr, 1024, 0);
  k_stats_bf<<<CH, b256, 0, stream>>>(raw5bf, sum5, sq5);
  k_final<<<dim3(NP / 32, CH / 32), b256, 0, stream>>>(raw5bf, slotC, sum5, sq5, f2g1, f2b1, out);
}

// Round 11
// 633.096 us; speedup vs baseline: 1.0328x; 1.0328x over previous
//
#include <hip/hip_runtime.h>
#include <cstddef>

#define HW 192
#define NP 36864          // H*W
#define CH 256
#define EDGES 294912
#define KSIG 289
#define SLOPE 0.01f
#define BNEPS 1e-5f
#define PADW 208          // padded image row (192 + 2*8)
#define PADSZ (PADW * PADW)   // 43264 u16 per channel
#define NP32 ((size_t)NP * 32)   // B-matrix K-slab stride (u16)

typedef unsigned short u16;
typedef __attribute__((ext_vector_type(8))) short bf16x8;
typedef __attribute__((ext_vector_type(4))) float f32x4;

__device__ __forceinline__ float leaky(float x) { return x >= 0.f ? x : SLOPE * x; }
__device__ __forceinline__ u16 f2bf(float x) {
  unsigned u = __float_as_uint(x);
  unsigned r = (u + 0x7fffu + ((u >> 16) & 1u)) >> 16;
  return (u16)r;
}
__device__ __forceinline__ float bf2f(unsigned h) { return __uint_as_float(h << 16); }
__device__ __forceinline__ void bnss(const float* sums, const float* sqs,
                                     const float* g, const float* b, int k,
                                     float& s, float& h) {
  float mean = sums[k] * (1.f / NP);
  float var = sqs[k] * (1.f / NP) - mean * mean;
  s = g[k] * rsqrtf(var + BNEPS);
  h = b[k] - mean * s;
}

// async global->LDS DMA: wave-uniform LDS base, per-lane global addr (lane*16B)
__device__ __forceinline__ void gload_lds16(const u16* g, u16* l) {
  __builtin_amdgcn_global_load_lds(
      (const __attribute__((address_space(1))) void*)g,
      (__attribute__((address_space(3))) void*)l, 16, 0, 0);
}

// ---- img = X^T (fp32 CxN) + padded leaky bf16 image (borders pre-zeroed) ------
__global__ __launch_bounds__(256) void k_transpose_pad(const float* __restrict__ src,
                                                       float* __restrict__ dst,
                                                       u16* __restrict__ pad) {
  __shared__ float tile[32][33];
  int s0 = blockIdx.x * 32, r0 = blockIdx.y * 32;   // s0 = channel, r0 = node
  int tx = threadIdx.x & 31, ty = threadIdx.x >> 5;
#pragma unroll
  for (int j = 0; j < 4; j++)
    tile[ty + 8 * j][tx] = src[(size_t)(r0 + ty + 8 * j) * CH + s0 + tx];
  __syncthreads();
  int n = r0 + tx;
  int y = n / HW, x = n - y * HW;
#pragma unroll
  for (int j = 0; j < 4; j++) {
    int c = s0 + ty + 8 * j;
    float v = tile[tx][ty + 8 * j];
    dst[(size_t)c * NP + n] = v;
    pad[(size_t)c * PADSZ + (y + 8) * PADW + x + 8] = f2bf(leaky(v));
  }
}

// ---- global Toeplitz build: Tg[c][ky][n][k] = w[c][ky][k-n] (bf16) ------------
__global__ __launch_bounds__(256) void k_mkT(const float* __restrict__ w,
                                             u16* __restrict__ Tg) {
  int c = blockIdx.x;
  const float* wc = w + c * 289;
  u16* tc = Tg + (size_t)c * 8704;
  for (int i = threadIdx.x; i < 8704; i += 256) {
    int ky = i >> 9, rem = i & 511, n = rem >> 5, k = rem & 31;
    int kx = k - n;
    float v = (kx >= 0 && kx < 17) ? wc[ky * 17 + kx] : 0.f;
    tc[i] = f2bf(v);
  }
}

// ---- weight fp32 -> bf16, K-SLAB TILED per matrix: (r,k) -> (k/32, r, k%32) ---
__global__ __launch_bounds__(256) void k_cvtW(const float* __restrict__ pw1,
                                              const float* __restrict__ f1w0,
                                              const float* __restrict__ f1w1,
                                              const float* __restrict__ dw1,
                                              const float* __restrict__ dw2,
                                              const float* __restrict__ f2w1,
                                              u16* __restrict__ out) {
  int i = blockIdx.x * 256 + threadIdx.x;   // 0..622591
  float v;
  int off, j, R, Klog;
  if (i < 65536)       { off = 0;      j = i;          v = pw1[j];  R = 256; Klog = 8; }
  else if (i < 131072) { off = 65536;  j = i - 65536;  v = f1w0[j]; R = 256; Klog = 8; }
  else if (i < 196608) { off = 131072; j = i - 131072; v = f1w1[j]; R = 256; Klog = 8; }
  else if (i < 262144) { off = 196608; j = i - 196608; v = dw1[j];  R = 256; Klog = 8; }
  else if (i < 360448) { off = 262144; j = i - 262144;
                         v = (j < KSIG * 256) ? dw2[j] : 0.f;       R = 384; Klog = 8; }
  else                 { off = 360448; j = i - 360448; v = f2w1[j]; R = 256; Klog = 10; }
  int r = j >> Klog, k = j & ((1 << Klog) - 1);
  int ni = off + (k >> 5) * (R * 32) + r * 32 + (k & 31);
  out[ni] = f2bf(v);
}

// ---------------- per-row stats, bf16 input (one block per row) ----------------
__global__ __launch_bounds__(256) void k_stats_bf(const u16* __restrict__ Xr,
                                                  float* __restrict__ sums,
                                                  float* __restrict__ sqs) {
  int row = blockIdx.x;
  int t = threadIdx.x;
  const uint4* p = (const uint4*)(Xr + (size_t)row * NP);
  float s = 0.f, q = 0.f;
  for (int i = t; i < NP / 8; i += 256) {
    uint4 v = p[i];
    unsigned w[4] = {v.x, v.y, v.z, v.w};
#pragma unroll
    for (int j = 0; j < 4; j++) {
      float a = bf2f(w[j] & 0xffffu), c = bf2f(w[j] >> 16);
      s += a + c; q += a * a + c * c;
    }
  }
  __shared__ float ss[256], qq[256];
  ss[t] = s; qq[t] = q;
  __syncthreads();
  for (int d = 128; d > 0; d >>= 1) {
    if (t < d) { ss[t] += ss[t + d]; qq[t] += qq[t + d]; }
    __syncthreads();
  }
  if (t == 0) { sums[row] = ss[0]; sqs[row] = qq[0]; }
}

// ---- bf16 (M x NP) -> bf16 transposed K-SLAB tiled, leaky(bn(x)) inline -------
__global__ __launch_bounds__(256) void k_cvtT_bf(const u16* __restrict__ in,
                                                 u16* __restrict__ outT,
                                                 const float* __restrict__ sums,
                                                 const float* __restrict__ sqs,
                                                 const float* __restrict__ g,
                                                 const float* __restrict__ b, int M) {
  __shared__ float tile[32][65];
  int n0 = blockIdx.x * 64, k0 = blockIdx.y * 32;
  int t = threadIdx.x;
  int k = t >> 3, cg = (t & 7) * 8;
  float s, h; bnss(sums, sqs, g, b, k0 + k, s, h);
  uint4 v = *(const uint4*)&in[(size_t)(k0 + k) * NP + n0 + cg];
  unsigned w[4] = {v.x, v.y, v.z, v.w};
#pragma unroll
  for (int j = 0; j < 4; j++) {
    tile[k][cg + 2 * j]     = leaky(fmaf(bf2f(w[j] & 0xffffu), s, h));
    tile[k][cg + 2 * j + 1] = leaky(fmaf(bf2f(w[j] >> 16), s, h));
  }
  __syncthreads();
  int n = t >> 2, kg = (t & 3) * 8;
  uint4 o;
  o.x = (unsigned)f2bf(tile[kg + 0][n]) | ((unsigned)f2bf(tile[kg + 1][n]) << 16);
  o.y = (unsigned)f2bf(tile[kg + 2][n]) | ((unsigned)f2bf(tile[kg + 3][n]) << 16);
  o.z = (unsigned)f2bf(tile[kg + 4][n]) | ((unsigned)f2bf(tile[kg + 5][n]) << 16);
  o.w = (unsigned)f2bf(tile[kg + 6][n]) | ((unsigned)f2bf(tile[kg + 7][n]) << 16);
  *(uint4*)&outT[(size_t)(k0 >> 5) * NP32 + (size_t)(n0 + n) * 32 + kg] = o;
}

// ---- fuse1: img2 = img + bn(raw1); img2 fp32 (CxN) + leaky(img2)^T tiled ------
__global__ __launch_bounds__(256) void k_fuse1(const float* __restrict__ base,
                                               const u16* __restrict__ raw,
                                               const float* __restrict__ sums,
                                               const float* __restrict__ sqs,
                                               const float* __restrict__ g,
                                               const float* __restrict__ b,
                                               float* __restrict__ img2,
                                               u16* __restrict__ outT) {
  __shared__ float tile[32][65];
  int n0 = blockIdx.x * 64, k0 = blockIdx.y * 32;
  int t = threadIdx.x;
#pragma unroll
  for (int i = 0; i < 2; i++) {
    int ci = i * 256 + t;
    int k = ci >> 4, cg = (ci & 15) * 4;
    float s, h; bnss(sums, sqs, g, b, k0 + k, s, h);
    size_t idx = (size_t)(k0 + k) * NP + n0 + cg;
    float4 bv = *(const float4*)&base[idx];
    uint2 rv = *(const uint2*)&raw[idx];
    float r0 = bf2f(rv.x & 0xffffu), r1 = bf2f(rv.x >> 16);
    float r2 = bf2f(rv.y & 0xffffu), r3 = bf2f(rv.y >> 16);
    float4 o;
    o.x = bv.x + fmaf(r0, s, h); o.y = bv.y + fmaf(r1, s, h);
    o.z = bv.z + fmaf(r2, s, h); o.w = bv.w + fmaf(r3, s, h);
    *(float4*)&img2[idx] = o;
    tile[k][cg]     = leaky(o.x);
    tile[k][cg + 1] = leaky(o.y);
    tile[k][cg + 2] = leaky(o.z);
    tile[k][cg + 3] = leaky(o.w);
  }
  __syncthreads();
  int n = t >> 2, kg = (t & 3) * 8;
  uint4 o;
  o.x = (unsigned)f2bf(tile[kg + 0][n]) | ((unsigned)f2bf(tile[kg + 1][n]) << 16);
  o.y = (unsigned)f2bf(tile[kg + 2][n]) | ((unsigned)f2bf(tile[kg + 3][n]) << 16);
  o.z = (unsigned)f2bf(tile[kg + 4][n]) | ((unsigned)f2bf(tile[kg + 5][n]) << 16);
  o.w = (unsigned)f2bf(tile[kg + 6][n]) | ((unsigned)f2bf(tile[kg + 7][n]) << 16);
  *(uint4*)&outT[(size_t)(k0 >> 5) * NP32 + (size_t)(n0 + n) * 32 + kg] = o;
}

// ---- fuse2: Xn = img2 + bn(raw3); Xn fp32 NxC + Xn bf16 NxC (row) + tiled -----
__global__ __launch_bounds__(256) void k_fuse2(const float* __restrict__ base,
                                               const u16* __restrict__ raw,
                                               const float* __restrict__ sums,
                                               const float* __restrict__ sqs,
                                               const float* __restrict__ g,
                                               const float* __restrict__ b,
                                               float* __restrict__ XnT,
                                               u16* __restrict__ outT,
                                               u16* __restrict__ outTt) {
  __shared__ float tile[32][65];
  int n0 = blockIdx.x * 64, k0 = blockIdx.y * 32;
  int t = threadIdx.x;
#pragma unroll
  for (int i = 0; i < 2; i++) {
    int ci = i * 256 + t;
    int k = ci >> 4, cg = (ci & 15) * 4;
    float s, h; bnss(sums, sqs, g, b, k0 + k, s, h);
    size_t idx = (size_t)(k0 + k) * NP + n0 + cg;
    float4 bv = *(const float4*)&base[idx];
    uint2 rv = *(const uint2*)&raw[idx];
    float r0 = bf2f(rv.x & 0xffffu), r1 = bf2f(rv.x >> 16);
    float r2 = bf2f(rv.y & 0xffffu), r3 = bf2f(rv.y >> 16);
    tile[k][cg]     = bv.x + fmaf(r0, s, h);
    tile[k][cg + 1] = bv.y + fmaf(r1, s, h);
    tile[k][cg + 2] = bv.z + fmaf(r2, s, h);
    tile[k][cg + 3] = bv.w + fmaf(r3, s, h);
  }
  __syncthreads();
  int n = t >> 2, kg = (t & 3) * 8;
  float4 f0 = {tile[kg + 0][n], tile[kg + 1][n], tile[kg + 2][n], tile[kg + 3][n]};
  float4 f1 = {tile[kg + 4][n], tile[kg + 5][n], tile[kg + 6][n], tile[kg + 7][n]};
  *(float4*)&XnT[(size_t)(n0 + n) * CH + k0 + kg] = f0;
  *(float4*)&XnT[(size_t)(n0 + n) * CH + k0 + kg + 4] = f1;
  uint4 o;
  o.x = (unsigned)f2bf(f0.x) | ((unsigned)f2bf(f0.y) << 16);
  o.y = (unsigned)f2bf(f0.z) | ((unsigned)f2bf(f0.w) << 16);
  o.z = (unsigned)f2bf(f1.x) | ((unsigned)f2bf(f1.y) << 16);
  o.w = (unsigned)f2bf(f1.z) | ((unsigned)f2bf(f1.w) << 16);
  *(uint4*)&outT[(size_t)(n0 + n) * CH + k0 + kg] = o;                    // row (agg)
  *(uint4*)&outTt[(size_t)(k0 >> 5) * NP32 + (size_t)(n0 + n) * 32 + kg] = o; // tiled (GEMM)
}

// ---------------- MFMA GEMM (generic, M via blockIdx.y) ------------------------
// m97 structure: K-slab global + LINEAR stride-32 LDS + global_load_lds width=16.
__global__ __launch_bounds__(256) void k_mgemm(const u16* __restrict__ A,
                                               const u16* __restrict__ Bt,
                                               float* __restrict__ Outf,
                                               u16* __restrict__ Outb,
                                               const float* __restrict__ bias,
                                               int K, int Mstore, int actout,
                                               int aslab) {
  __shared__ u16 As[128 * 32];
  __shared__ u16 Bs[128 * 32];
  int t = threadIdx.x;
  int lane = t & 63, wave = t >> 6;
  int wm = (wave >> 1) * 64, wn = (wave & 1) * 64;
  int m0 = blockIdx.y * 128, n0 = blockIdx.x * 128;
  int r = lane & 15, q = lane >> 4;
  f32x4 acc[4][4];
#pragma unroll
  for (int a = 0; a < 4; a++)
#pragma unroll
    for (int b = 0; b < 4; b++) acc[a][b] = (f32x4){0.f, 0.f, 0.f, 0.f};

  int kiters = K >> 5;
  for (int ki = 0; ki < kiters; ki++) {
    const u16* Ag = A + (size_t)ki * aslab + (size_t)m0 * 32;
    const u16* Bg = Bt + (size_t)ki * NP32 + (size_t)n0 * 32;
#pragma unroll
    for (int j = 0; j < 4; j++) {
      int c = wave * 4 + j;          // 0..15, wave-uniform
      if (c < 8) gload_lds16(Ag + c * 512 + lane * 8, As + c * 512);
      else       gload_lds16(Bg + (c - 8) * 512 + lane * 8, Bs + (c - 8) * 512);
    }
    __syncthreads();                 // drains vmcnt -> LDS filled
    bf16x8 af[4], bfr[4];
#pragma unroll
    for (int mt = 0; mt < 4; mt++)
      af[mt] = *(const bf16x8*)&As[(wm + mt * 16 + r) * 32 + q * 8];
#pragma unroll
    for (int nt = 0; nt < 4; nt++)
      bfr[nt] = *(const bf16x8*)&Bs[(wn + nt * 16 + r) * 32 + q * 8];
#pragma unroll
    for (int mt = 0; mt < 4; mt++)
#pragma unroll
      for (int nt = 0; nt < 4; nt++)
        acc[mt][nt] = __builtin_amdgcn_mfma_f32_16x16x32_bf16(af[mt], bfr[nt], acc[mt][nt], 0, 0, 0);
    __syncthreads();                 // reads done before next overwrite
  }
#pragma unroll
  for (int mt = 0; mt < 4; mt++) {
    int mrow = m0 + wm + mt * 16 + q * 4;
#pragma unroll
    for (int i = 0; i < 4; i++) {
      int m = mrow + i;
      if (m >= Mstore) continue;
      float bs = bias ? bias[m] : 0.f;
#pragma unroll
      for (int nt = 0; nt < 4; nt++) {
        float v = acc[mt][nt][i] + bs;
        if (actout) v = leaky(v);
        size_t oi = (size_t)m * NP + n0 + wn + nt * 16 + r;
        if (Outb) Outb[oi] = f2bf(v); else Outf[oi] = v;
      }
    }
  }
}

// ---------------- MFMA GEMM, M=256, m97-style staging --------------------------
// r9-proven body. Optional OutbT: K-slab-tiled bf16 output (vectorized uint2
// stores). NO fused stats (r1/r8/r10: epilogue reductions = poison).
__global__ __launch_bounds__(512) void k_mgemm256(const u16* __restrict__ A,
                                                  const u16* __restrict__ Bt,
                                                  float* __restrict__ Outf,
                                                  u16* __restrict__ Outb,
                                                  u16* __restrict__ OutbT,
                                                  const float* __restrict__ bias,
                                                  int K, int actout) {
  __shared__ u16 As[256 * 32];
  __shared__ u16 Bs[128 * 32];
  int t = threadIdx.x;
  int lane = t & 63, wave = t >> 6;
  int wm = (wave >> 1) * 64, wn = (wave & 1) * 64;   // wm 0..192, wn 0/64
  int n0 = blockIdx.x * 128;
  int r = lane & 15, q = lane >> 4;
  f32x4 acc[4][4];
#pragma unroll
  for (int a = 0; a < 4; a++)
#pragma unroll
    for (int b = 0; b < 4; b++) acc[a][b] = (f32x4){0.f, 0.f, 0.f, 0.f};

  int kiters = K >> 5;
  for (int ki = 0; ki < kiters; ki++) {
    const u16* Ag = A + (size_t)ki * 8192;                     // 256 rows * 32
    const u16* Bg = Bt + (size_t)ki * NP32 + (size_t)n0 * 32;
#pragma unroll
    for (int j = 0; j < 3; j++) {
      int c = wave * 3 + j;          // 0..23, wave-uniform
      if (c < 16) gload_lds16(Ag + c * 512 + lane * 8, As + c * 512);
      else        gload_lds16(Bg + (c - 16) * 512 + lane * 8, Bs + (c - 16) * 512);
    }
    __syncthreads();                 // drains vmcnt -> LDS filled
    bf16x8 af[4], bfr[4];
#pragma unroll
    for (int mt = 0; mt < 4; mt++)
      af[mt] = *(const bf16x8*)&As[(wm + mt * 16 + r) * 32 + q * 8];
#pragma unroll
    for (int nt = 0; nt < 4; nt++)
      bfr[nt] = *(const bf16x8*)&Bs[(wn + nt * 16 + r) * 32 + q * 8];
#pragma unroll
    for (int mt = 0; mt < 4; mt++)
#pragma unroll
      for (int nt = 0; nt < 4; nt++)
        acc[mt][nt] = __builtin_amdgcn_mfma_f32_16x16x32_bf16(af[mt], bfr[nt], acc[mt][nt], 0, 0, 0);
    __syncthreads();                 // reads done before next overwrite
  }
#pragma unroll
  for (int mt = 0; mt < 4; mt++) {
    int mrow = wm + mt * 16 + q * 4;
    if (OutbT) {
      int slab = (wm + mt * 16) >> 5;           // m-slab index
      int ko = (mt & 1) * 16 + q * 4;           // (m & 31) base for i=0
      float b0 = bias ? bias[mrow + 0] : 0.f;
      float b1 = bias ? bias[mrow + 1] : 0.f;
      float b2 = bias ? bias[mrow + 2] : 0.f;
      float b3 = bias ? bias[mrow + 3] : 0.f;
#pragma unroll
      for (int nt = 0; nt < 4; nt++) {
        int n = n0 + wn + nt * 16 + r;
        float w0 = acc[mt][nt][0] + b0, w1 = acc[mt][nt][1] + b1;
        float w2 = acc[mt][nt][2] + b2, w3 = acc[mt][nt][3] + b3;
        if (actout) { w0 = leaky(w0); w1 = leaky(w1); w2 = leaky(w2); w3 = leaky(w3); }
        uint2 pk;
        pk.x = (unsigned)f2bf(w0) | ((unsigned)f2bf(w1) << 16);
        pk.y = (unsigned)f2bf(w2) | ((unsigned)f2bf(w3) << 16);
        *(uint2*)&OutbT[(size_t)slab * NP32 + (size_t)n * 32 + ko] = pk;
      }
      continue;
    }
#pragma unroll
    for (int i = 0; i < 4; i++) {
      int m = mrow + i;
      float bs = bias ? bias[m] : 0.f;
#pragma unroll
      for (int nt = 0; nt < 4; nt++) {
        float v = acc[mt][nt][i] + bs;
        if (actout) v = leaky(v);
        size_t oi = (size_t)m * NP + n0 + wn + nt * 16 + r;
        if (Outb) Outb[oi] = f2bf(v); else Outf[oi] = v;
      }
    }
  }
}

// ---------------- depthwise 17x17 conv via MFMA, padded bf16 input -------------
__global__ __launch_bounds__(256) void k_dwconv17(const u16* __restrict__ pad,
                                                  const u16* __restrict__ Tg,
                                                  u16* __restrict__ outb) {
  int c = blockIdx.y;
  int tile = blockIdx.x;                  // 0..8
  int ty0 = (tile / 3) * 64, tx0 = (tile % 3) * 64;
  __shared__ u16 smIn[80 * 88];
  __shared__ u16 smT[17 * 16 * 40];
  const u16* pc = pad + (size_t)c * PADSZ;
  for (int cc = threadIdx.x; cc < 800; cc += 256) {
    int rr = cc / 10, j = cc - rr * 10;
    uint4 v = *(const uint4*)(pc + (ty0 + rr) * PADW + tx0 + j * 8);
    *(uint4*)(smIn + rr * 88 + j * 8) = v;
  }
  const u16* tc = Tg + (size_t)c * 8704;
  for (int cc = threadIdx.x; cc < 1088; cc += 256) {
    int rr = cc >> 2, j = cc & 3;
    uint4 v = *(const uint4*)(tc + rr * 32 + j * 8);
    *(uint4*)(smT + rr * 40 + j * 8) = v;
  }
  __syncthreads();
  int lane = threadIdx.x & 63, wave = threadIdx.x >> 6;
  int wy = wave * 16;
  int r = lane & 15, q = lane >> 4;
  f32x4 acc[4];
#pragma unroll
  for (int xt = 0; xt < 4; xt++) acc[xt] = (f32x4){0.f, 0.f, 0.f, 0.f};
#pragma unroll
  for (int ky = 0; ky < 17; ky++) {
    bf16x8 bfrag = *(const bf16x8*)&smT[(ky * 16 + r) * 40 + q * 8];
    int rowA = wy + r + ky;
#pragma unroll
    for (int xt = 0; xt < 4; xt++) {
      bf16x8 afrag = *(const bf16x8*)&smIn[rowA * 88 + xt * 16 + q * 8];
      acc[xt] = __builtin_amdgcn_mfma_f32_16x16x32_bf16(afrag, bfrag, acc[xt], 0, 0, 0);
    }
  }
  u16* oc = outb + (size_t)c * NP;
#pragma unroll
  for (int xt = 0; xt < 4; xt++) {
    int x = tx0 + xt * 16 + r;
#pragma unroll
    for (int i = 0; i < 4; i++) {
      int y = ty0 + wy + q * 4 + i;
      oc[y * HW + x] = f2bf(acc[xt][i]);
    }
  }
}

// ---------------- grouped 3x3 conv, row-sliding, no LDS, no barrier ------------
__global__ __launch_bounds__(256) void k_conv3x4(const float* __restrict__ in,
                                                 const float* __restrict__ w,
                                                 u16* __restrict__ out) {
  int wave = threadIdx.x >> 6, lane = threadIdx.x & 63;
  int c = blockIdx.y;
  int y = blockIdx.x * 4 + wave;
  const float* wc = w + (size_t)(4 * c) * 9;
  float wr[36];
#pragma unroll
  for (int k = 0; k < 36; k++) wr[k] = wc[k];
  float acc[4][3];
#pragma unroll
  for (int oc = 0; oc < 4; oc++)
#pragma unroll
    for (int s = 0; s < 3; s++) acc[oc][s] = 0.f;
  const float* base = in + (size_t)c * NP;
#pragma unroll
  for (int ky = 0; ky < 3; ky++) {
    int ry = y + ky - 1;
    if (ry < 0 || ry >= HW) continue;
    const float* rp = base + ry * HW;
    float a0 = leaky(rp[lane]);
    float a1 = leaky(rp[64 + lane]);
    float a2 = leaky(rp[128 + lane]);
    float e0 = __shfl(a0, 63), e1 = __shfl(a1, 63);
    float b1 = __shfl(a1, 0),  b2 = __shfl(a2, 0);
    float l0 = __shfl_up(a0, 1); if (lane == 0) l0 = 0.f;
    float l1 = __shfl_up(a1, 1); if (lane == 0) l1 = e0;
    float l2 = __shfl_up(a2, 1); if (lane == 0) l2 = e1;
    float r0 = __shfl_down(a0, 1); if (lane == 63) r0 = b1;
    float r1 = __shfl_down(a1, 1); if (lane == 63) r1 = b2;
    float r2 = __shfl_down(a2, 1); if (lane == 63) r2 = 0.f;
#pragma unroll
    for (int oc = 0; oc < 4; oc++) {
      float w0 = wr[oc * 9 + ky * 3], w1 = wr[oc * 9 + ky * 3 + 1], w2 = wr[oc * 9 + ky * 3 + 2];
      acc[oc][0] = fmaf(w0, l0, fmaf(w1, a0, fmaf(w2, r0, acc[oc][0])));
      acc[oc][1] = fmaf(w0, l1, fmaf(w1, a1, fmaf(w2, r1, acc[oc][1])));
      acc[oc][2] = fmaf(w0, l2, fmaf(w1, a2, fmaf(w2, r2, acc[oc][2])));
    }
  }
  size_t ob = (size_t)(4 * c) * NP + (size_t)y * HW + lane;
#pragma unroll
  for (int oc = 0; oc < 4; oc++) {
    out[ob + (size_t)oc * NP]       = f2bf(acc[oc][0]);
    out[ob + (size_t)oc * NP + 64]  = f2bf(acc[oc][1]);
    out[ob + (size_t)oc * NP + 128] = f2bf(acc[oc][2]);
  }
}

// ---------------- edge scores + dst histogram ----------------------------------
__global__ __launch_bounds__(256) void k_edge(const int* __restrict__ info,
                                              const float* __restrict__ msk,
                                              const float* __restrict__ sig,
                                              float* __restrict__ aij,
                                              int* __restrict__ counts) {
  int e = blockIdx.x * 256 + threadIdx.x;
  int4 ii = ((const int4*)info)[e];
  float s = sig[(size_t)ii.y * NP + ii.x] + sig[(size_t)ii.w * NP + ii.z];
  s = fminf(fmaxf(s, -5.f), 5.f);
  aij[e] = expf(s) * msk[e];
  atomicAdd(&counts[ii.z], 1);
}

// ---------------- counting-sort by dst -----------------------------------------
__global__ __launch_bounds__(256) void k_scan1(const int* __restrict__ counts,
                                               int* __restrict__ offsets,
                                               int* __restrict__ bsum) {
  __shared__ int sm[256];
  int t = threadIdx.x;
  int i = blockIdx.x * 256 + t;
  int v = counts[i];
  sm[t] = v;
  __syncthreads();
  for (int d = 1; d < 256; d <<= 1) {
    int add = (t >= d) ? sm[t - d] : 0;
    __syncthreads();
    sm[t] += add;
    __syncthreads();
  }
  offsets[i] = sm[t] - v;
  if (t == 255) bsum[blockIdx.x] = sm[255];
}
__global__ __launch_bounds__(256) void k_scan2(const int* __restrict__ bsum,
                                               int* __restrict__ boff) {
  __shared__ int sm[256];
  int t = threadIdx.x;
  int v = (t < 144) ? bsum[t] : 0;
  sm[t] = v;
  __syncthreads();
  for (int d = 1; d < 256; d <<= 1) {
    int add = (t >= d) ? sm[t - d] : 0;
    __syncthreads();
    sm[t] += add;
    __syncthreads();
  }
  boff[t] = sm[t] - v;
}
__global__ __launch_bounds__(256) void k_scan3(int* __restrict__ offsets,
                                               const int* __restrict__ boff,
                                               int* __restrict__ cursor) {
  int i = blockIdx.x * 256 + threadIdx.x;
  int o = offsets[i] + boff[blockIdx.x];
  offsets[i] = o;
  cursor[i] = o;
  if (i == 0) offsets[NP] = EDGES;
}
// scatter (src, aij) pre-sorted by dst
__global__ __launch_bounds__(256) void k_scatter(const int* __restrict__ info,
                                                 const float* __restrict__ aij,
                                                 int* __restrict__ cursor,
                                                 int* __restrict__ srcs,
                                                 float* __restrict__ aijw) {
  int e = blockIdx.x * 256 + threadIdx.x;
  int4 ii = ((const int4*)info)[e];
  int pos = atomicAdd(&cursor[ii.z], 1);
  srcs[pos] = ii.x;
  aijw[pos] = aij[e];
}

// ---------------- per-node aggregation: half-wave per edge stream --------------
__global__ __launch_bounds__(256) void k_agg(const int* __restrict__ offsets,
                                             const int* __restrict__ srcs,
                                             const float* __restrict__ aijw,
                                             const u16* __restrict__ XnBf,
                                             u16* __restrict__ XtrBf) {
  int wave = threadIdx.x >> 6, lane = threadIdx.x & 63;
  int node = blockIdx.x * 4 + wave;
  int o0 = offsets[node], o1 = offsets[node + 1];
  int half = lane >> 5, l32 = lane & 31;
  float acc[8] = {0.f, 0.f, 0.f, 0.f, 0.f, 0.f, 0.f, 0.f};
  float asum = 0.f;
  int i = o0 + half;
  for (; i + 2 < o1; i += 4) {
    int s0 = srcs[i], s1 = srcs[i + 2];
    float a0 = aijw[i], a1 = aijw[i + 2];
    uint4 v0 = ((const uint4*)(XnBf + (size_t)s0 * CH))[l32];
    uint4 v1 = ((const uint4*)(XnBf + (size_t)s1 * CH))[l32];
    unsigned w0[4] = {v0.x, v0.y, v0.z, v0.w};
    unsigned w1[4] = {v1.x, v1.y, v1.z, v1.w};
#pragma unroll
    for (int j = 0; j < 4; j++) {
      acc[2 * j]     = fmaf(a0, bf2f(w0[j] & 0xffffu), acc[2 * j]);
      acc[2 * j + 1] = fmaf(a0, bf2f(w0[j] >> 16),     acc[2 * j + 1]);
      acc[2 * j]     = fmaf(a1, bf2f(w1[j] & 0xffffu), acc[2 * j]);
      acc[2 * j + 1] = fmaf(a1, bf2f(w1[j] >> 16),     acc[2 * j + 1]);
    }
    asum += a0 + a1;
  }
  for (; i < o1; i += 2) {
    int s = srcs[i];
    float a = aijw[i];
    uint4 v = ((const uint4*)(XnBf + (size_t)s * CH))[l32];
    unsigned w[4] = {v.x, v.y, v.z, v.w};
#pragma unroll
    for (int j = 0; j < 4; j++) {
      acc[2 * j]     = fmaf(a, bf2f(w[j] & 0xffffu), acc[2 * j]);
      acc[2 * j + 1] = fmaf(a, bf2f(w[j] >> 16),     acc[2 * j + 1]);
    }
    asum += a;
  }
#pragma unroll
  for (int j = 0; j < 8; j++) acc[j] += __shfl_xor(acc[j], 32, 64);
  asum += __shfl_xor(asum, 32, 64);
  if (half == 0) {
    float inv = 1.f / (asum + 1e-5f);
    uint4 o;
    o.x = (unsigned)f2bf(acc[0] * inv) | ((unsigned)f2bf(acc[1] * inv) << 16);
    o.y = (unsigned)f2bf(acc[2] * inv) | ((unsigned)f2bf(acc[3] * inv) << 16);
    o.z = (unsigned)f2bf(acc[4] * inv) | ((unsigned)f2bf(acc[5] * inv) << 16);
    o.w = (unsigned)f2bf(acc[6] * inv) | ((unsigned)f2bf(acc[7] * inv) << 16);
    ((uint4*)(XtrBf + (size_t)node * CH))[l32] = o;
  }
}

// ---------------- bn1d stats (bf16 input) --------------------------------------
__global__ __launch_bounds__(256) void k_colstats(const u16* __restrict__ Xt,
                                                  float* __restrict__ sums,
                                                  float* __restrict__ sqs) {
  int c = threadIdx.x;
  float s = 0.f, q = 0.f;
  for (int n = blockIdx.x; n < NP; n += gridDim.x) {
    float v = bf2f(Xt[(size_t)n * CH + c]);
    s += v; q += v * v;
  }
  atomicAdd(&sums[c], s);
  atomicAdd(&sqs[c], q);
}

// ---------------- img4 = transpose(Xn + bn1d(Xtr bf16))  (N x C -> C x N) ------
__global__ __launch_bounds__(256) void k_mkimg4(const float* __restrict__ Xn,
                                                const u16* __restrict__ XtrBf,
                                                const float* __restrict__ sums,
                                                const float* __restrict__ sqs,
                                                const float* __restrict__ g,
                                                const float* __restrict__ b,
                                                float* __restrict__ img4) {
  __shared__ float tile[32][33];
  int c0 = blockIdx.x * 32, n0 = blockIdx.y * 32;
  int tx = threadIdx.x & 31, ty = threadIdx.x >> 5;
  int c = c0 + tx;
  float s, h; bnss(sums, sqs, g, b, c, s, h);
#pragma unroll
  for (int j = 0; j < 4; j++) {
    size_t idx = (size_t)(n0 + ty + 8 * j) * CH + c;
    tile[ty + 8 * j][tx] = Xn[idx] + fmaf(bf2f(XtrBf[idx]), s, h);
  }
  __syncthreads();
#pragma unroll
  for (int j = 0; j < 4; j++) {
    int cc = c0 + ty + 8 * j;
    img4[(size_t)cc * NP + n0 + tx] = tile[tx][ty + 8 * j];
  }
}

// ---------------- out(N x C) = transpose(bn(raw5 bf16) + img4) -----------------
__global__ __launch_bounds__(256) void k_final(const u16* __restrict__ raw5,
                                               const float* __restrict__ img4,
                                               const float* __restrict__ sums,
                                               const float* __restrict__ sqs,
                                               const float* __restrict__ g,
                                               const float* __restrict__ b,
                                               float* __restrict__ out) {
  __shared__ float tile[32][33];
  int n0 = blockIdx.x * 32, c0 = blockIdx.y * 32;
  int tx = threadIdx.x & 31, ty = threadIdx.x >> 5;
#pragma unroll
  for (int j = 0; j < 4; j++) {
    int c = c0 + ty + 8 * j;
    float s, h; bnss(sums, sqs, g, b, c, s, h);
    size_t idx = (size_t)c * NP + n0 + tx;
    tile[ty + 8 * j][tx] = fmaf(bf2f(raw5[idx]), s, h) + img4[idx];
  }
  __syncthreads();
#pragma unroll
  for (int j = 0; j < 4; j++) {
    int n = n0 + ty + 8 * j;
    out[(size_t)n * CH + c0 + tx] = tile[tx][ty + 8 * j];
  }
}

extern "C" void kernel_launch(void* const* d_in, const int* in_sizes, int n_in,
                              void* d_out, int out_size, void* d_ws, size_t ws_size,
                              hipStream_t stream) {
  (void)in_sizes; (void)n_in; (void)out_size; (void)ws_size;
  const float* X    = (const float*)d_in[0];
  const int*   info = (const int*)d_in[1];
  const float* msk  = (const float*)d_in[2];
  const float* pw0  = (const float*)d_in[3];
  const float* pg0  = (const float*)d_in[4];
  const float* pb0  = (const float*)d_in[5];
  const float* pw1  = (const float*)d_in[6];
  const float* pg1  = (const float*)d_in[7];
  const float* pb1  = (const float*)d_in[8];
  const float* f1w0 = (const float*)d_in[9];
  const float* f1g0 = (const float*)d_in[10];
  const float* f1b0 = (const float*)d_in[11];
  const float* f1w1 = (const float*)d_in[12];
  const float* f1g1 = (const float*)d_in[13];
  const float* f1b1 = (const float*)d_in[14];
  const float* dw1  = (const float*)d_in[15];
  const float* db1  = (const float*)d_in[16];
  const float* dw2  = (const float*)d_in[17];
  const float* db2  = (const float*)d_in[18];
  const float* bng  = (const float*)d_in[19];
  const float* bnb  = (const float*)d_in[20];
  const float* f2w0 = (const float*)d_in[21];
  const float* f2g0 = (const float*)d_in[22];
  const float* f2b0 = (const float*)d_in[23];
  const float* f2w1 = (const float*)d_in[24];
  const float* f2g1 = (const float*)d_in[25];
  const float* f2b1 = (const float*)d_in[26];
  float* out = (float*)d_out;

  float* ws = (float*)d_ws;
  float* sum0 = ws + 0;    float* sq0 = ws + 256;
  float* sum1 = ws + 512;  float* sq1 = ws + 768;
  float* sum2 = ws + 1024; float* sq2 = ws + 1280;
  float* sum3 = ws + 1536; float* sq3 = ws + 1792;
  float* sum5 = ws + 2048; float* sq5 = ws + 2304;
  float* sumT = ws + 2560; float* sqT = ws + 2816;   // atomic targets, zeroed
  float* sum4 = ws + 3072; float* sq4 = ws + 4096;   // 1024 each
  int* counts  = (int*)(ws + 8192);
  int* offsets = (int*)(ws + 45056);
  int* cursor  = (int*)(ws + 82176);
  int* bsum    = (int*)(ws + 119296);
  int* boff    = (int*)(ws + 119552);
  int* srcs    = (int*)(ws + 131072);      // EDGES
  float* aij   = ws + 425984;              // EDGES (unsorted)
  const size_t S = (size_t)NP * CH;        // 9437184 words
  float* slotD = ws + 720896;
  float* slotB = slotD + S;
  float* slotA = slotB + S;
  float* slotC = slotA + S;
  u16* bfB  = (u16*)(slotC + S);           // NP x 256 bf16
  u16* bfH  = bfB + S;                     // raw0/raw1/raw2/raw3/h-bf16
  float* sigT = (float*)(bfH + S);         // KSIG x NP fp32
  u16* bfW  = (u16*)(sigT + (size_t)KSIG * NP);
  float* aijw = (float*)(bfW + 622592);    // EDGES, sorted by dst
  // early-phase aliases into dead fp32 slots:
  u16* Ppad = (u16*)slotC;                 // 256ch x 208x208 bf16 padded leaky img
  u16* Tg   = (u16*)slotD;                 // 256 x 8704 Toeplitz
  u16* raw4bf  = (u16*)slotB;              // 1024 x NP bf16, spans slotB+slotA
  u16* bfT1024 = bfB;                      // NP x 1024 bf16 (K-slab tiled)
  u16* XtrBf   = (u16*)slotD;              // N x C bf16 (img2/Tg dead)
  u16* raw5bf  = (u16*)slotB;              // C x NP bf16 (raw4bf dead after cvtT_bf)
  u16* bfBt    = (u16*)sigT;               // NP x 256 bf16 K-slab tiled (dis GEMM B);
                                           // dead before k_mgemm writes sigT

  hipMemsetAsync(ws, 0, 5120 * sizeof(float), stream);
  hipMemsetAsync(counts, 0, NP * sizeof(int), stream);
  hipMemsetAsync(Ppad, 0, (size_t)PADSZ * CH * sizeof(u16), stream);

  dim3 b256(256), b512(512);
  k_cvtW<<<2432, b256, 0, stream>>>(pw1, f1w0, f1w1, dw1, dw2, f2w1, bfW);
  k_mkT<<<CH, b256, 0, stream>>>(pw0, Tg);
  // img = X^T -> slotA ; padded leaky bf16 -> Ppad
  k_transpose_pad<<<dim3(CH / 32, NP / 32), b256, 0, stream>>>(X, slotA, Ppad);
  // ppm depthwise -> raw0 bf16 (bfH)
  k_dwconv17<<<dim3(9, CH), b256, 0, stream>>>(Ppad, Tg, bfH);
  k_stats_bf<<<CH, b256, 0, stream>>>(bfH, sum0, sq0);
  k_cvtT_bf<<<dim3(NP / 64, 8), b256, 0, stream>>>(bfH, bfB, sum0, sq0, pg0, pb0, CH);
  // ppm 1x1 -> raw1 bf16 (bfH; raw0 dead)
  k_mgemm256<<<NP / 128, b512, 0, stream>>>(bfW, bfB, nullptr, bfH, nullptr, nullptr, CH, 0);
  k_stats_bf<<<CH, b256, 0, stream>>>(bfH, sum1, sq1);
  // img2 = img + bn(raw1) -> slotD (Tg dead) ; bfB = leaky(img2)^T tiled
  k_fuse1<<<dim3(NP / 64, 8), b256, 0, stream>>>(slotA, bfH, sum1, sq1, pg1, pb1, slotD, bfB);
  // ffn1 conv0 -> raw2 bf16 (bfH)
  k_mgemm256<<<NP / 128, b512, 0, stream>>>(bfW + 65536, bfB, nullptr, bfH, nullptr, nullptr, CH, 0);
  k_stats_bf<<<CH, b256, 0, stream>>>(bfH, sum2, sq2);
  k_cvtT_bf<<<dim3(NP / 64, 8), b256, 0, stream>>>(bfH, bfB, sum2, sq2, f1g0, f1b0, CH);
  // ffn1 conv1 -> raw3 bf16 (bfH)
  k_mgemm256<<<NP / 128, b512, 0, stream>>>(bfW + 131072, bfB, nullptr, bfH, nullptr, nullptr, CH, 0);
  k_stats_bf<<<CH, b256, 0, stream>>>(bfH, sum3, sq3);
  // Xn = img2 + bn(raw3): fp32 NxC -> slotA ; bf16 NxC row -> bfB ; tiled -> bfBt
  k_fuse2<<<dim3(NP / 64, 8), b256, 0, stream>>>(slotD, bfH, sum3, sq3, f1g1, f1b1, slotA, bfB, bfBt);
  // dis: h -> bfH DIRECTLY in K-slab tiled bf16, bias+leaky, uint2 tiled stores
  k_mgemm256<<<NP / 128, b512, 0, stream>>>(bfW + 196608, bfBt, nullptr, nullptr, bfH, db1, CH, 1);
  k_mgemm<<<dim3(NP / 128, 3), b256, 0, stream>>>(bfW + 262144, bfH, sigT, nullptr, db2, CH, KSIG, 0, 12288);
  // edges
  k_edge<<<EDGES / 256, b256, 0, stream>>>(info, msk, sigT, aij, counts);
  k_scan1<<<NP / 256, b256, 0, stream>>>(counts, offsets, bsum);
  k_scan2<<<1, b256, 0, stream>>>(bsum, boff);
  k_scan3<<<NP / 256, b256, 0, stream>>>(offsets, boff, cursor);
  k_scatter<<<EDGES / 256, b256, 0, stream>>>(info, aij, cursor, srcs, aijw);
  // Xtr bf16 -> XtrBf (slotD; img2 dead)  [bfB row-major]
  k_agg<<<NP / 4, b256, 0, stream>>>(offsets, srcs, aijw, bfB, XtrBf);
  k_colstats<<<288, b256, 0, stream>>>(XtrBf, sumT, sqT);
  // img4 -> slotC (Ppad dead)
  k_mkimg4<<<dim3(CH / 32, NP / 32), b256, 0, stream>>>(slotA, XtrBf, sumT, sqT, bng, bnb, slotC);
  // ffn2 grouped 3x3 -> raw4bf (slotB+slotA; Xn fp32 dead)
  k_conv3x4<<<dim3(48, CH), b256, 0, stream>>>(slotC, f2w0, raw4bf);
  k_stats_bf<<<1024, b256, 0, stream>>>(raw4bf, sum4, sq4);
  k_cvtT_bf<<<dim3(NP / 64, 32), b256, 0, stream>>>(raw4bf, bfT1024, sum4, sq4, f2g0, f2b0, 1024);
  // ffn2 1x1 -> raw5 bf16 (slotB; raw4bf consumed)
  k_mgemm256<<<NP / 128, b512, 0, stream>>>(bfW + 360448, bfT1024, nullptr, raw5bf, nullptr, nullptr, 1024, 0);
  k_stats_bf<<<CH, b256, 0, stream>>>(raw5bf, sum5, sq5);
  k_final<<<dim3(NP / 32, CH / 32), b256, 0, stream>>>(raw5bf, slotC, sum5, sq5, f2g1, f2b1, out);
}

// Round 12
// 627.375 us; speedup vs baseline: 1.0422x; 1.0091x over previous
//
#include <hip/hip_runtime.h>
#include <cstddef>

#define HW 192
#define NP 36864          // H*W
#define CH 256
#define EDGES 294912
#define KSIG 289
#define SLOPE 0.01f
#define BNEPS 1e-5f
#define PADW 208          // padded image row (192 + 2*8)
#define PADSZ (PADW * PADW)   // 43264 u16 per channel
#define NP32 ((size_t)NP * 32)   // B-matrix K-slab stride (u16)
#define BN 144            // GEMM N-tile: NP/144 = 256 blocks = exactly 1/CU

typedef unsigned short u16;
typedef __attribute__((ext_vector_type(8))) short bf16x8;
typedef __attribute__((ext_vector_type(4))) float f32x4;

__device__ __forceinline__ float leaky(float x) { return x >= 0.f ? x : SLOPE * x; }
__device__ __forceinline__ u16 f2bf(float x) {
  unsigned u = __float_as_uint(x);
  unsigned r = (u + 0x7fffu + ((u >> 16) & 1u)) >> 16;
  return (u16)r;
}
__device__ __forceinline__ float bf2f(unsigned h) { return __uint_as_float(h << 16); }
__device__ __forceinline__ void bnss(const float* sums, const float* sqs,
                                     const float* g, const float* b, int k,
                                     float& s, float& h) {
  float mean = sums[k] * (1.f / NP);
  float var = sqs[k] * (1.f / NP) - mean * mean;
  s = g[k] * rsqrtf(var + BNEPS);
  h = b[k] - mean * s;
}

// async global->LDS DMA: wave-uniform LDS base, per-lane global addr (lane*16B)
__device__ __forceinline__ void gload_lds16(const u16* g, u16* l) {
  __builtin_amdgcn_global_load_lds(
      (const __attribute__((address_space(1))) void*)g,
      (__attribute__((address_space(3))) void*)l, 16, 0, 0);
}

// ---- img = X^T (fp32 CxN) + padded leaky bf16 image (borders pre-zeroed) ------
__global__ __launch_bounds__(256) void k_transpose_pad(const float* __restrict__ src,
                                                       float* __restrict__ dst,
                                                       u16* __restrict__ pad) {
  __shared__ float tile[32][33];
  int s0 = blockIdx.x * 32, r0 = blockIdx.y * 32;   // s0 = channel, r0 = node
  int tx = threadIdx.x & 31, ty = threadIdx.x >> 5;
#pragma unroll
  for (int j = 0; j < 4; j++)
    tile[ty + 8 * j][tx] = src[(size_t)(r0 + ty + 8 * j) * CH + s0 + tx];
  __syncthreads();
  int n = r0 + tx;
  int y = n / HW, x = n - y * HW;
#pragma unroll
  for (int j = 0; j < 4; j++) {
    int c = s0 + ty + 8 * j;
    float v = tile[tx][ty + 8 * j];
    dst[(size_t)c * NP + n] = v;
    pad[(size_t)c * PADSZ + (y + 8) * PADW + x + 8] = f2bf(leaky(v));
  }
}

// ---- global Toeplitz build: Tg[c][ky][n][k] = w[c][ky][k-n] (bf16) ------------
__global__ __launch_bounds__(256) void k_mkT(const float* __restrict__ w,
                                             u16* __restrict__ Tg) {
  int c = blockIdx.x;
  const float* wc = w + c * 289;
  u16* tc = Tg + (size_t)c * 8704;
  for (int i = threadIdx.x; i < 8704; i += 256) {
    int ky = i >> 9, rem = i & 511, n = rem >> 5, k = rem & 31;
    int kx = k - n;
    float v = (kx >= 0 && kx < 17) ? wc[ky * 17 + kx] : 0.f;
    tc[i] = f2bf(v);
  }
}

// ---- weight fp32 -> bf16, K-SLAB TILED per matrix: (r,k) -> (k/32, r, k%32) ---
__global__ __launch_bounds__(256) void k_cvtW(const float* __restrict__ pw1,
                                              const float* __restrict__ f1w0,
                                              const float* __restrict__ f1w1,
                                              const float* __restrict__ dw1,
                                              const float* __restrict__ dw2,
                                              const float* __restrict__ f2w1,
                                              u16* __restrict__ out) {
  int i = blockIdx.x * 256 + threadIdx.x;   // 0..622591
  float v;
  int off, j, R, Klog;
  if (i < 65536)       { off = 0;      j = i;          v = pw1[j];  R = 256; Klog = 8; }
  else if (i < 131072) { off = 65536;  j = i - 65536;  v = f1w0[j]; R = 256; Klog = 8; }
  else if (i < 196608) { off = 131072; j = i - 131072; v = f1w1[j]; R = 256; Klog = 8; }
  else if (i < 262144) { off = 196608; j = i - 196608; v = dw1[j];  R = 256; Klog = 8; }
  else if (i < 360448) { off = 262144; j = i - 262144;
                         v = (j < KSIG * 256) ? dw2[j] : 0.f;       R = 384; Klog = 8; }
  else                 { off = 360448; j = i - 360448; v = f2w1[j]; R = 256; Klog = 10; }
  int r = j >> Klog, k = j & ((1 << Klog) - 1);
  int ni = off + (k >> 5) * (R * 32) + r * 32 + (k & 31);
  out[ni] = f2bf(v);
}

// ---------------- per-row stats, bf16 input (one block per row) ----------------
__global__ __launch_bounds__(256) void k_stats_bf(const u16* __restrict__ Xr,
                                                  float* __restrict__ sums,
                                                  float* __restrict__ sqs) {
  int row = blockIdx.x;
  int t = threadIdx.x;
  const uint4* p = (const uint4*)(Xr + (size_t)row * NP);
  float s = 0.f, q = 0.f;
  for (int i = t; i < NP / 8; i += 256) {
    uint4 v = p[i];
    unsigned w[4] = {v.x, v.y, v.z, v.w};
#pragma unroll
    for (int j = 0; j < 4; j++) {
      float a = bf2f(w[j] & 0xffffu), c = bf2f(w[j] >> 16);
      s += a + c; q += a * a + c * c;
    }
  }
  __shared__ float ss[256], qq[256];
  ss[t] = s; qq[t] = q;
  __syncthreads();
  for (int d = 128; d > 0; d >>= 1) {
    if (t < d) { ss[t] += ss[t + d]; qq[t] += qq[t + d]; }
    __syncthreads();
  }
  if (t == 0) { sums[row] = ss[0]; sqs[row] = qq[0]; }
}

// ---- bf16 (M x NP) -> bf16 transposed K-SLAB tiled, leaky(bn(x)) inline -------
__global__ __launch_bounds__(256) void k_cvtT_bf(const u16* __restrict__ in,
                                                 u16* __restrict__ outT,
                                                 const float* __restrict__ sums,
                                                 const float* __restrict__ sqs,
                                                 const float* __restrict__ g,
                                                 const float* __restrict__ b, int M) {
  __shared__ float tile[32][65];
  int n0 = blockIdx.x * 64, k0 = blockIdx.y * 32;
  int t = threadIdx.x;
  int k = t >> 3, cg = (t & 7) * 8;
  float s, h; bnss(sums, sqs, g, b, k0 + k, s, h);
  uint4 v = *(const uint4*)&in[(size_t)(k0 + k) * NP + n0 + cg];
  unsigned w[4] = {v.x, v.y, v.z, v.w};
#pragma unroll
  for (int j = 0; j < 4; j++) {
    tile[k][cg + 2 * j]     = leaky(fmaf(bf2f(w[j] & 0xffffu), s, h));
    tile[k][cg + 2 * j + 1] = leaky(fmaf(bf2f(w[j] >> 16), s, h));
  }
  __syncthreads();
  int n = t >> 2, kg = (t & 3) * 8;
  uint4 o;
  o.x = (unsigned)f2bf(tile[kg + 0][n]) | ((unsigned)f2bf(tile[kg + 1][n]) << 16);
  o.y = (unsigned)f2bf(tile[kg + 2][n]) | ((unsigned)f2bf(tile[kg + 3][n]) << 16);
  o.z = (unsigned)f2bf(tile[kg + 4][n]) | ((unsigned)f2bf(tile[kg + 5][n]) << 16);
  o.w = (unsigned)f2bf(tile[kg + 6][n]) | ((unsigned)f2bf(tile[kg + 7][n]) << 16);
  *(uint4*)&outT[(size_t)(k0 >> 5) * NP32 + (size_t)(n0 + n) * 32 + kg] = o;
}

// ---- fuse1: img2 = img + bn(raw1); img2 fp32 (CxN) + leaky(img2)^T tiled ------
__global__ __launch_bounds__(256) void k_fuse1(const float* __restrict__ base,
                                               const u16* __restrict__ raw,
                                               const float* __restrict__ sums,
                                               const float* __restrict__ sqs,
                                               const float* __restrict__ g,
                                               const float* __restrict__ b,
                                               float* __restrict__ img2,
                                               u16* __restrict__ outT) {
  __shared__ float tile[32][65];
  int n0 = blockIdx.x * 64, k0 = blockIdx.y * 32;
  int t = threadIdx.x;
#pragma unroll
  for (int i = 0; i < 2; i++) {
    int ci = i * 256 + t;
    int k = ci >> 4, cg = (ci & 15) * 4;
    float s, h; bnss(sums, sqs, g, b, k0 + k, s, h);
    size_t idx = (size_t)(k0 + k) * NP + n0 + cg;
    float4 bv = *(const float4*)&base[idx];
    uint2 rv = *(const uint2*)&raw[idx];
    float r0 = bf2f(rv.x & 0xffffu), r1 = bf2f(rv.x >> 16);
    float r2 = bf2f(rv.y & 0xffffu), r3 = bf2f(rv.y >> 16);
    float4 o;
    o.x = bv.x + fmaf(r0, s, h); o.y = bv.y + fmaf(r1, s, h);
    o.z = bv.z + fmaf(r2, s, h); o.w = bv.w + fmaf(r3, s, h);
    *(float4*)&img2[idx] = o;
    tile[k][cg]     = leaky(o.x);
    tile[k][cg + 1] = leaky(o.y);
    tile[k][cg + 2] = leaky(o.z);
    tile[k][cg + 3] = leaky(o.w);
  }
  __syncthreads();
  int n = t >> 2, kg = (t & 3) * 8;
  uint4 o;
  o.x = (unsigned)f2bf(tile[kg + 0][n]) | ((unsigned)f2bf(tile[kg + 1][n]) << 16);
  o.y = (unsigned)f2bf(tile[kg + 2][n]) | ((unsigned)f2bf(tile[kg + 3][n]) << 16);
  o.z = (unsigned)f2bf(tile[kg + 4][n]) | ((unsigned)f2bf(tile[kg + 5][n]) << 16);
  o.w = (unsigned)f2bf(tile[kg + 6][n]) | ((unsigned)f2bf(tile[kg + 7][n]) << 16);
  *(uint4*)&outT[(size_t)(k0 >> 5) * NP32 + (size_t)(n0 + n) * 32 + kg] = o;
}

// ---- fuse2: Xn = img2 + bn(raw3); Xn fp32 NxC + Xn bf16 NxC (row) + tiled -----
__global__ __launch_bounds__(256) void k_fuse2(const float* __restrict__ base,
                                               const u16* __restrict__ raw,
                                               const float* __restrict__ sums,
                                               const float* __restrict__ sqs,
                                               const float* __restrict__ g,
                                               const float* __restrict__ b,
                                               float* __restrict__ XnT,
                                               u16* __restrict__ outT,
                                               u16* __restrict__ outTt) {
  __shared__ float tile[32][65];
  int n0 = blockIdx.x * 64, k0 = blockIdx.y * 32;
  int t = threadIdx.x;
#pragma unroll
  for (int i = 0; i < 2; i++) {
    int ci = i * 256 + t;
    int k = ci >> 4, cg = (ci & 15) * 4;
    float s, h; bnss(sums, sqs, g, b, k0 + k, s, h);
    size_t idx = (size_t)(k0 + k) * NP + n0 + cg;
    float4 bv = *(const float4*)&base[idx];
    uint2 rv = *(const uint2*)&raw[idx];
    float r0 = bf2f(rv.x & 0xffffu), r1 = bf2f(rv.x >> 16);
    float r2 = bf2f(rv.y & 0xffffu), r3 = bf2f(rv.y >> 16);
    tile[k][cg]     = bv.x + fmaf(r0, s, h);
    tile[k][cg + 1] = bv.y + fmaf(r1, s, h);
    tile[k][cg + 2] = bv.z + fmaf(r2, s, h);
    tile[k][cg + 3] = bv.w + fmaf(r3, s, h);
  }
  __syncthreads();
  int n = t >> 2, kg = (t & 3) * 8;
  float4 f0 = {tile[kg + 0][n], tile[kg + 1][n], tile[kg + 2][n], tile[kg + 3][n]};
  float4 f1 = {tile[kg + 4][n], tile[kg + 5][n], tile[kg + 6][n], tile[kg + 7][n]};
  *(float4*)&XnT[(size_t)(n0 + n) * CH + k0 + kg] = f0;
  *(float4*)&XnT[(size_t)(n0 + n) * CH + k0 + kg + 4] = f1;
  uint4 o;
  o.x = (unsigned)f2bf(f0.x) | ((unsigned)f2bf(f0.y) << 16);
  o.y = (unsigned)f2bf(f0.z) | ((unsigned)f2bf(f0.w) << 16);
  o.z = (unsigned)f2bf(f1.x) | ((unsigned)f2bf(f1.y) << 16);
  o.w = (unsigned)f2bf(f1.z) | ((unsigned)f2bf(f1.w) << 16);
  *(uint4*)&outT[(size_t)(n0 + n) * CH + k0 + kg] = o;                    // row (agg)
  *(uint4*)&outTt[(size_t)(k0 >> 5) * NP32 + (size_t)(n0 + n) * 32 + kg] = o; // tiled (GEMM)
}

// ---------------- MFMA GEMM (generic, M via blockIdx.y) ------------------------
// m97 structure: K-slab global + LINEAR stride-32 LDS + global_load_lds width=16.
__global__ __launch_bounds__(256) void k_mgemm(const u16* __restrict__ A,
                                               const u16* __restrict__ Bt,
                                               float* __restrict__ Outf,
                                               u16* __restrict__ Outb,
                                               const float* __restrict__ bias,
                                               int K, int Mstore, int actout,
                                               int aslab) {
  __shared__ u16 As[128 * 32];
  __shared__ u16 Bs[128 * 32];
  int t = threadIdx.x;
  int lane = t & 63, wave = t >> 6;
  int wm = (wave >> 1) * 64, wn = (wave & 1) * 64;
  int m0 = blockIdx.y * 128, n0 = blockIdx.x * 128;
  int r = lane & 15, q = lane >> 4;
  f32x4 acc[4][4];
#pragma unroll
  for (int a = 0; a < 4; a++)
#pragma unroll
    for (int b = 0; b < 4; b++) acc[a][b] = (f32x4){0.f, 0.f, 0.f, 0.f};

  int kiters = K >> 5;
  for (int ki = 0; ki < kiters; ki++) {
    const u16* Ag = A + (size_t)ki * aslab + (size_t)m0 * 32;
    const u16* Bg = Bt + (size_t)ki * NP32 + (size_t)n0 * 32;
#pragma unroll
    for (int j = 0; j < 4; j++) {
      int c = wave * 4 + j;          // 0..15, wave-uniform
      if (c < 8) gload_lds16(Ag + c * 512 + lane * 8, As + c * 512);
      else       gload_lds16(Bg + (c - 8) * 512 + lane * 8, Bs + (c - 8) * 512);
    }
    __syncthreads();                 // drains vmcnt -> LDS filled
    bf16x8 af[4], bfr[4];
#pragma unroll
    for (int mt = 0; mt < 4; mt++)
      af[mt] = *(const bf16x8*)&As[(wm + mt * 16 + r) * 32 + q * 8];
#pragma unroll
    for (int nt = 0; nt < 4; nt++)
      bfr[nt] = *(const bf16x8*)&Bs[(wn + nt * 16 + r) * 32 + q * 8];
#pragma unroll
    for (int mt = 0; mt < 4; mt++)
#pragma unroll
      for (int nt = 0; nt < 4; nt++)
        acc[mt][nt] = __builtin_amdgcn_mfma_f32_16x16x32_bf16(af[mt], bfr[nt], acc[mt][nt], 0, 0, 0);
    __syncthreads();                 // reads done before next overwrite
  }
#pragma unroll
  for (int mt = 0; mt < 4; mt++) {
    int mrow = m0 + wm + mt * 16 + q * 4;
#pragma unroll
    for (int i = 0; i < 4; i++) {
      int m = mrow + i;
      if (m >= Mstore) continue;
      float bs = bias ? bias[m] : 0.f;
#pragma unroll
      for (int nt = 0; nt < 4; nt++) {
        float v = acc[mt][nt][i] + bs;
        if (actout) v = leaky(v);
        size_t oi = (size_t)m * NP + n0 + wn + nt * 16 + r;
        if (Outb) Outb[oi] = f2bf(v); else Outf[oi] = v;
      }
    }
  }
}

// ---------------- MFMA GEMM, M=256, BN=144: grid = NP/144 = 256 = 1 block/CU ---
// Tail-quantization fix: r0-r11 makespan was always ceil(grid/256) x per-block
// time (288 blocks -> 32 CUs carry 2 blocks -> 2x makespan). BN=144 gives a
// zero-tail grid. 8 waves x (32 rows x 144 cols): wm = wave*32, acc[2][9].
// Staging 25 x 1KB chunks (A 16 + B 9) via gload_lds16; LDS 25.6KB; same
// 2-barrier loop and MFMA k-order as r9 (bit-identical outputs).
__global__ __launch_bounds__(512) void k_mgemm256(const u16* __restrict__ A,
                                                  const u16* __restrict__ Bt,
                                                  float* __restrict__ Outf,
                                                  u16* __restrict__ Outb,
                                                  u16* __restrict__ OutbT,
                                                  const float* __restrict__ bias,
                                                  int K, int actout) {
  __shared__ u16 As[256 * 32];     // 16 KB
  __shared__ u16 Bs[BN * 32];      // 9 KB
  int t = threadIdx.x;
  int lane = t & 63, wave = t >> 6;
  int wm = wave * 32;              // 8 waves x 32 rows
  int n0 = blockIdx.x * BN;
  int r = lane & 15, q = lane >> 4;
  f32x4 acc[2][9];
#pragma unroll
  for (int a = 0; a < 2; a++)
#pragma unroll
    for (int b = 0; b < 9; b++) acc[a][b] = (f32x4){0.f, 0.f, 0.f, 0.f};

  int kiters = K >> 5;
  for (int ki = 0; ki < kiters; ki++) {
    const u16* Ag = A + (size_t)ki * 8192;                     // 256 rows * 32
    const u16* Bg = Bt + (size_t)ki * NP32 + (size_t)n0 * 32;
#pragma unroll
    for (int j = 0; j < 4; j++) {
      int c = wave * 4 + j;          // 0..31, wave-uniform; 25 live chunks
      if (c < 16)      gload_lds16(Ag + c * 512 + lane * 8, As + c * 512);
      else if (c < 25) gload_lds16(Bg + (c - 16) * 512 + lane * 8, Bs + (c - 16) * 512);
    }
    __syncthreads();                 // drains vmcnt -> LDS filled
    bf16x8 bfr[9];
#pragma unroll
    for (int nt = 0; nt < 9; nt++)
      bfr[nt] = *(const bf16x8*)&Bs[(nt * 16 + r) * 32 + q * 8];
#pragma unroll
    for (int mt = 0; mt < 2; mt++) {
      bf16x8 af = *(const bf16x8*)&As[(wm + mt * 16 + r) * 32 + q * 8];
#pragma unroll
      for (int nt = 0; nt < 9; nt++)
        acc[mt][nt] = __builtin_amdgcn_mfma_f32_16x16x32_bf16(af, bfr[nt], acc[mt][nt], 0, 0, 0);
    }
    __syncthreads();                 // reads done before next overwrite
  }
#pragma unroll
  for (int mt = 0; mt < 2; mt++) {
    int mrow = wm + mt * 16 + q * 4;
    if (OutbT) {
      int slab = wave;                          // m>>5 == wave for all mt here
      int ko = mt * 16 + q * 4;                 // (m & 31) base for i=0
      float b0 = bias ? bias[mrow + 0] : 0.f;
      float b1 = bias ? bias[mrow + 1] : 0.f;
      float b2 = bias ? bias[mrow + 2] : 0.f;
      float b3 = bias ? bias[mrow + 3] : 0.f;
#pragma unroll
      for (int nt = 0; nt < 9; nt++) {
        int n = n0 + nt * 16 + r;
        float w0 = acc[mt][nt][0] + b0, w1 = acc[mt][nt][1] + b1;
        float w2 = acc[mt][nt][2] + b2, w3 = acc[mt][nt][3] + b3;
        if (actout) { w0 = leaky(w0); w1 = leaky(w1); w2 = leaky(w2); w3 = leaky(w3); }
        uint2 pk;
        pk.x = (unsigned)f2bf(w0) | ((unsigned)f2bf(w1) << 16);
        pk.y = (unsigned)f2bf(w2) | ((unsigned)f2bf(w3) << 16);
        *(uint2*)&OutbT[(size_t)slab * NP32 + (size_t)n * 32 + ko] = pk;
      }
      continue;
    }
#pragma unroll
    for (int i = 0; i < 4; i++) {
      int m = mrow + i;
      float bs = bias ? bias[m] : 0.f;
#pragma unroll
      for (int nt = 0; nt < 9; nt++) {
        float v = acc[mt][nt][i] + bs;
        if (actout) v = leaky(v);
        size_t oi = (size_t)m * NP + n0 + nt * 16 + r;
        if (Outb) Outb[oi] = f2bf(v); else Outf[oi] = v;
      }
    }
  }
}

// ---------------- depthwise 17x17 conv via MFMA, padded bf16 input -------------
__global__ __launch_bounds__(256) void k_dwconv17(const u16* __restrict__ pad,
                                                  const u16* __restrict__ Tg,
                                                  u16* __restrict__ outb) {
  int c = blockIdx.y;
  int tile = blockIdx.x;                  // 0..8
  int ty0 = (tile / 3) * 64, tx0 = (tile % 3) * 64;
  __shared__ u16 smIn[80 * 88];
  __shared__ u16 smT[17 * 16 * 40];
  const u16* pc = pad + (size_t)c * PADSZ;
  for (int cc = threadIdx.x; cc < 800; cc += 256) {
    int rr = cc / 10, j = cc - rr * 10;
    uint4 v = *(const uint4*)(pc + (ty0 + rr) * PADW + tx0 + j * 8);
    *(uint4*)(smIn + rr * 88 + j * 8) = v;
  }
  const u16* tc = Tg + (size_t)c * 8704;
  for (int cc = threadIdx.x; cc < 1088; cc += 256) {
    int rr = cc >> 2, j = cc & 3;
    uint4 v = *(const uint4*)(tc + rr * 32 + j * 8);
    *(uint4*)(smT + rr * 40 + j * 8) = v;
  }
  __syncthreads();
  int lane = threadIdx.x & 63, wave = threadIdx.x >> 6;
  int wy = wave * 16;
  int r = lane & 15, q = lane >> 4;
  f32x4 acc[4];
#pragma unroll
  for (int xt = 0; xt < 4; xt++) acc[xt] = (f32x4){0.f, 0.f, 0.f, 0.f};
#pragma unroll
  for (int ky = 0; ky < 17; ky++) {
    bf16x8 bfrag = *(const bf16x8*)&smT[(ky * 16 + r) * 40 + q * 8];
    int rowA = wy + r + ky;
#pragma unroll
    for (int xt = 0; xt < 4; xt++) {
      bf16x8 afrag = *(const bf16x8*)&smIn[rowA * 88 + xt * 16 + q * 8];
      acc[xt] = __builtin_amdgcn_mfma_f32_16x16x32_bf16(afrag, bfrag, acc[xt], 0, 0, 0);
    }
  }
  u16* oc = outb + (size_t)c * NP;
#pragma unroll
  for (int xt = 0; xt < 4; xt++) {
    int x = tx0 + xt * 16 + r;
#pragma unroll
    for (int i = 0; i < 4; i++) {
      int y = ty0 + wy + q * 4 + i;
      oc[y * HW + x] = f2bf(acc[xt][i]);
    }
  }
}

// ---------------- grouped 3x3 conv, row-sliding, no LDS, no barrier ------------
__global__ __launch_bounds__(256) void k_conv3x4(const float* __restrict__ in,
                                                 const float* __restrict__ w,
                                                 u16* __restrict__ out) {
  int wave = threadIdx.x >> 6, lane = threadIdx.x & 63;
  int c = blockIdx.y;
  int y = blockIdx.x * 4 + wave;
  const float* wc = w + (size_t)(4 * c) * 9;
  float wr[36];
#pragma unroll
  for (int k = 0; k < 36; k++) wr[k] = wc[k];
  float acc[4][3];
#pragma unroll
  for (int oc = 0; oc < 4; oc++)
#pragma unroll
    for (int s = 0; s < 3; s++) acc[oc][s] = 0.f;
  const float* base = in + (size_t)c * NP;
#pragma unroll
  for (int ky = 0; ky < 3; ky++) {
    int ry = y + ky - 1;
    if (ry < 0 || ry >= HW) continue;
    const float* rp = base + ry * HW;
    float a0 = leaky(rp[lane]);
    float a1 = leaky(rp[64 + lane]);
    float a2 = leaky(rp[128 + lane]);
    float e0 = __shfl(a0, 63), e1 = __shfl(a1, 63);
    float b1 = __shfl(a1, 0),  b2 = __shfl(a2, 0);
    float l0 = __shfl_up(a0, 1); if (lane == 0) l0 = 0.f;
    float l1 = __shfl_up(a1, 1); if (lane == 0) l1 = e0;
    float l2 = __shfl_up(a2, 1); if (lane == 0) l2 = e1;
    float r0 = __shfl_down(a0, 1); if (lane == 63) r0 = b1;
    float r1 = __shfl_down(a1, 1); if (lane == 63) r1 = b2;
    float r2 = __shfl_down(a2, 1); if (lane == 63) r2 = 0.f;
#pragma unroll
    for (int oc = 0; oc < 4; oc++) {
      float w0 = wr[oc * 9 + ky * 3], w1 = wr[oc * 9 + ky * 3 + 1], w2 = wr[oc * 9 + ky * 3 + 2];
      acc[oc][0] = fmaf(w0, l0, fmaf(w1, a0, fmaf(w2, r0, acc[oc][0])));
      acc[oc][1] = fmaf(w0, l1, fmaf(w1, a1, fmaf(w2, r1, acc[oc][1])));
      acc[oc][2] = fmaf(w0, l2, fmaf(w1, a2, fmaf(w2, r2, acc[oc][2])));
    }
  }
  size_t ob = (size_t)(4 * c) * NP + (size_t)y * HW + lane;
#pragma unroll
  for (int oc = 0; oc < 4; oc++) {
    out[ob + (size_t)oc * NP]       = f2bf(acc[oc][0]);
    out[ob + (size_t)oc * NP + 64]  = f2bf(acc[oc][1]);
    out[ob + (size_t)oc * NP + 128] = f2bf(acc[oc][2]);
  }
}

// ---------------- edge scores + dst histogram ----------------------------------
__global__ __launch_bounds__(256) void k_edge(const int* __restrict__ info,
                                              const float* __restrict__ msk,
                                              const float* __restrict__ sig,
                                              float* __restrict__ aij,
                                              int* __restrict__ counts) {
  int e = blockIdx.x * 256 + threadIdx.x;
  int4 ii = ((const int4*)info)[e];
  float s = sig[(size_t)ii.y * NP + ii.x] + sig[(size_t)ii.w * NP + ii.z];
  s = fminf(fmaxf(s, -5.f), 5.f);
  aij[e] = expf(s) * msk[e];
  atomicAdd(&counts[ii.z], 1);
}

// ---------------- counting-sort by dst -----------------------------------------
__global__ __launch_bounds__(256) void k_scan1(const int* __restrict__ counts,
                                               int* __restrict__ offsets,
                                               int* __restrict__ bsum) {
  __shared__ int sm[256];
  int t = threadIdx.x;
  int i = blockIdx.x * 256 + t;
  int v = counts[i];
  sm[t] = v;
  __syncthreads();
  for (int d = 1; d < 256; d <<= 1) {
    int add = (t >= d) ? sm[t - d] : 0;
    __syncthreads();
    sm[t] += add;
    __syncthreads();
  }
  offsets[i] = sm[t] - v;
  if (t == 255) bsum[blockIdx.x] = sm[255];
}
__global__ __launch_bounds__(256) void k_scan2(const int* __restrict__ bsum,
                                               int* __restrict__ boff) {
  __shared__ int sm[256];
  int t = threadIdx.x;
  int v = (t < 144) ? bsum[t] : 0;
  sm[t] = v;
  __syncthreads();
  for (int d = 1; d < 256; d <<= 1) {
    int add = (t >= d) ? sm[t - d] : 0;
    __syncthreads();
    sm[t] += add;
    __syncthreads();
  }
  boff[t] = sm[t] - v;
}
__global__ __launch_bounds__(256) void k_scan3(int* __restrict__ offsets,
                                               const int* __restrict__ boff,
                                               int* __restrict__ cursor) {
  int i = blockIdx.x * 256 + threadIdx.x;
  int o = offsets[i] + boff[blockIdx.x];
  offsets[i] = o;
  cursor[i] = o;
  if (i == 0) offsets[NP] = EDGES;
}
// scatter (src, aij) pre-sorted by dst
__global__ __launch_bounds__(256) void k_scatter(const int* __restrict__ info,
                                                 const float* __restrict__ aij,
                                                 int* __restrict__ cursor,
                                                 int* __restrict__ srcs,
                                                 float* __restrict__ aijw) {
  int e = blockIdx.x * 256 + threadIdx.x;
  int4 ii = ((const int4*)info)[e];
  int pos = atomicAdd(&cursor[ii.z], 1);
  srcs[pos] = ii.x;
  aijw[pos] = aij[e];
}

// ---------------- per-node aggregation: half-wave per edge stream --------------
__global__ __launch_bounds__(256) void k_agg(const int* __restrict__ offsets,
                                             const int* __restrict__ srcs,
                                             const float* __restrict__ aijw,
                                             const u16* __restrict__ XnBf,
                                             u16* __restrict__ XtrBf) {
  int wave = threadIdx.x >> 6, lane = threadIdx.x & 63;
  int node = blockIdx.x * 4 + wave;
  int o0 = offsets[node], o1 = offsets[node + 1];
  int half = lane >> 5, l32 = lane & 31;
  float acc[8] = {0.f, 0.f, 0.f, 0.f, 0.f, 0.f, 0.f, 0.f};
  float asum = 0.f;
  int i = o0 + half;
  for (; i + 2 < o1; i += 4) {
    int s0 = srcs[i], s1 = srcs[i + 2];
    float a0 = aijw[i], a1 = aijw[i + 2];
    uint4 v0 = ((const uint4*)(XnBf + (size_t)s0 * CH))[l32];
    uint4 v1 = ((const uint4*)(XnBf + (size_t)s1 * CH))[l32];
    unsigned w0[4] = {v0.x, v0.y, v0.z, v0.w};
    unsigned w1[4] = {v1.x, v1.y, v1.z, v1.w};
#pragma unroll
    for (int j = 0; j < 4; j++) {
      acc[2 * j]     = fmaf(a0, bf2f(w0[j] & 0xffffu), acc[2 * j]);
      acc[2 * j + 1] = fmaf(a0, bf2f(w0[j] >> 16),     acc[2 * j + 1]);
      acc[2 * j]     = fmaf(a1, bf2f(w1[j] & 0xffffu), acc[2 * j]);
      acc[2 * j + 1] = fmaf(a1, bf2f(w1[j] >> 16),     acc[2 * j + 1]);
    }
    asum += a0 + a1;
  }
  for (; i < o1; i += 2) {
    int s = srcs[i];
    float a = aijw[i];
    uint4 v = ((const uint4*)(XnBf + (size_t)s * CH))[l32];
    unsigned w[4] = {v.x, v.y, v.z, v.w};
#pragma unroll
    for (int j = 0; j < 4; j++) {
      acc[2 * j]     = fmaf(a, bf2f(w[j] & 0xffffu), acc[2 * j]);
      acc[2 * j + 1] = fmaf(a, bf2f(w[j] >> 16),     acc[2 * j + 1]);
    }
    asum += a;
  }
#pragma unroll
  for (int j = 0; j < 8; j++) acc[j] += __shfl_xor(acc[j], 32, 64);
  asum += __shfl_xor(asum, 32, 64);
  if (half == 0) {
    float inv = 1.f / (asum + 1e-5f);
    uint4 o;
    o.x = (unsigned)f2bf(acc[0] * inv) | ((unsigned)f2bf(acc[1] * inv) << 16);
    o.y = (unsigned)f2bf(acc[2] * inv) | ((unsigned)f2bf(acc[3] * inv) << 16);
    o.z = (unsigned)f2bf(acc[4] * inv) | ((unsigned)f2bf(acc[5] * inv) << 16);
    o.w = (unsigned)f2bf(acc[6] * inv) | ((unsigned)f2bf(acc[7] * inv) << 16);
    ((uint4*)(XtrBf + (size_t)node * CH))[l32] = o;
  }
}

// ---------------- bn1d stats (bf16 input) --------------------------------------
__global__ __launch_bounds__(256) void k_colstats(const u16* __restrict__ Xt,
                                                  float* __restrict__ sums,
                                                  float* __restrict__ sqs) {
  int c = threadIdx.x;
  float s = 0.f, q = 0.f;
  for (int n = blockIdx.x; n < NP; n += gridDim.x) {
    float v = bf2f(Xt[(size_t)n * CH + c]);
    s += v; q += v * v;
  }
  atomicAdd(&sums[c], s);
  atomicAdd(&sqs[c], q);
}

// ---------------- img4 = transpose(Xn + bn1d(Xtr bf16))  (N x C -> C x N) ------
__global__ __launch_bounds__(256) void k_mkimg4(const float* __restrict__ Xn,
                                                const u16* __restrict__ XtrBf,
                                                const float* __restrict__ sums,
                                                const float* __restrict__ sqs,
                                                const float* __restrict__ g,
                                                const float* __restrict__ b,
                                                float* __restrict__ img4) {
  __shared__ float tile[32][33];
  int c0 = blockIdx.x * 32, n0 = blockIdx.y * 32;
  int tx = threadIdx.x & 31, ty = threadIdx.x >> 5;
  int c = c0 + tx;
  float s, h; bnss(sums, sqs, g, b, c, s, h);
#pragma unroll
  for (int j = 0; j < 4; j++) {
    size_t idx = (size_t)(n0 + ty + 8 * j) * CH + c;
    tile[ty + 8 * j][tx] = Xn[idx] + fmaf(bf2f(XtrBf[idx]), s, h);
  }
  __syncthreads();
#pragma unroll
  for (int j = 0; j < 4; j++) {
    int cc = c0 + ty + 8 * j;
    img4[(size_t)cc * NP + n0 + tx] = tile[tx][ty + 8 * j];
  }
}

// ---------------- out(N x C) = transpose(bn(raw5 bf16) + img4) -----------------
__global__ __launch_bounds__(256) void k_final(const u16* __restrict__ raw5,
                                               const float* __restrict__ img4,
                                               const float* __restrict__ sums,
                                               const float* __restrict__ sqs,
                                               const float* __restrict__ g,
                                               const float* __restrict__ b,
                                               float* __restrict__ out) {
  __shared__ float tile[32][33];
  int n0 = blockIdx.x * 32, c0 = blockIdx.y * 32;
  int tx = threadIdx.x & 31, ty = threadIdx.x >> 5;
#pragma unroll
  for (int j = 0; j < 4; j++) {
    int c = c0 + ty + 8 * j;
    float s, h; bnss(sums, sqs, g, b, c, s, h);
    size_t idx = (size_t)c * NP + n0 + tx;
    tile[ty + 8 * j][tx] = fmaf(bf2f(raw5[idx]), s, h) + img4[idx];
  }
  __syncthreads();
#pragma unroll
  for (int j = 0; j < 4; j++) {
    int n = n0 + ty + 8 * j;
    out[(size_t)n * CH + c0 + tx] = tile[tx][ty + 8 * j];
  }
}

extern "C" void kernel_launch(void* const* d_in, const int* in_sizes, int n_in,
                              void* d_out, int out_size, void* d_ws, size_t ws_size,
                              hipStream_t stream) {
  (void)in_sizes; (void)n_in; (void)out_size; (void)ws_size;
  const float* X    = (const float*)d_in[0];
  const int*   info = (const int*)d_in[1];
  const float* msk  = (const float*)d_in[2];
  const float* pw0  = (const float*)d_in[3];
  const float* pg0  = (const float*)d_in[4];
  const float* pb0  = (const float*)d_in[5];
  const float* pw1  = (const float*)d_in[6];
  const float* pg1  = (const float*)d_in[7];
  const float* pb1  = (const float*)d_in[8];
  const float* f1w0 = (const float*)d_in[9];
  const float* f1g0 = (const float*)d_in[10];
  const float* f1b0 = (const float*)d_in[11];
  const float* f1w1 = (const float*)d_in[12];
  const float* f1g1 = (const float*)d_in[13];
  const float* f1b1 = (const float*)d_in[14];
  const float* dw1  = (const float*)d_in[15];
  const float* db1  = (const float*)d_in[16];
  const float* dw2  = (const float*)d_in[17];
  const float* db2  = (const float*)d_in[18];
  const float* bng  = (const float*)d_in[19];
  const float* bnb  = (const float*)d_in[20];
  const float* f2w0 = (const float*)d_in[21];
  const float* f2g0 = (const float*)d_in[22];
  const float* f2b0 = (const float*)d_in[23];
  const float* f2w1 = (const float*)d_in[24];
  const float* f2g1 = (const float*)d_in[25];
  const float* f2b1 = (const float*)d_in[26];
  float* out = (float*)d_out;

  float* ws = (float*)d_ws;
  float* sum0 = ws + 0;    float* sq0 = ws + 256;
  float* sum1 = ws + 512;  float* sq1 = ws + 768;
  float* sum2 = ws + 1024; float* sq2 = ws + 1280;
  float* sum3 = ws + 1536; float* sq3 = ws + 1792;
  float* sum5 = ws + 2048; float* sq5 = ws + 2304;
  float* sumT = ws + 2560; float* sqT = ws + 2816;   // atomic targets, zeroed
  float* sum4 = ws + 3072; float* sq4 = ws + 4096;   // 1024 each
  int* counts  = (int*)(ws + 8192);
  int* offsets = (int*)(ws + 45056);
  int* cursor  = (int*)(ws + 82176);
  int* bsum    = (int*)(ws + 119296);
  int* boff    = (int*)(ws + 119552);
  int* srcs    = (int*)(ws + 131072);      // EDGES
  float* aij   = ws + 425984;              // EDGES (unsorted)
  const size_t S = (size_t)NP * CH;        // 9437184 words
  float* slotD = ws + 720896;
  float* slotB = slotD + S;
  float* slotA = slotB + S;
  float* slotC = slotA + S;
  u16* bfB  = (u16*)(slotC + S);           // NP x 256 bf16
  u16* bfH  = bfB + S;                     // raw0/raw1/raw2/raw3/h-bf16
  float* sigT = (float*)(bfH + S);         // KSIG x NP fp32
  u16* bfW  = (u16*)(sigT + (size_t)KSIG * NP);
  float* aijw = (float*)(bfW + 622592);    // EDGES, sorted by dst
  // early-phase aliases into dead fp32 slots:
  u16* Ppad = (u16*)slotC;                 // 256ch x 208x208 bf16 padded leaky img
  u16* Tg   = (u16*)slotD;                 // 256 x 8704 Toeplitz
  u16* raw4bf  = (u16*)slotB;              // 1024 x NP bf16, spans slotB+slotA
  u16* bfT1024 = bfB;                      // NP x 1024 bf16 (K-slab tiled)
  u16* XtrBf   = (u16*)slotD;              // N x C bf16 (img2/Tg dead)
  u16* raw5bf  = (u16*)slotB;              // C x NP bf16 (raw4bf dead after cvtT_bf)
  u16* bfBt    = (u16*)sigT;               // NP x 256 bf16 K-slab tiled (dis GEMM B);
                                           // dead before k_mgemm writes sigT

  hipMemsetAsync(ws, 0, 5120 * sizeof(float), stream);
  hipMemsetAsync(counts, 0, NP * sizeof(int), stream);
  hipMemsetAsync(Ppad, 0, (size_t)PADSZ * CH * sizeof(u16), stream);

  dim3 b256(256), b512(512);
  k_cvtW<<<2432, b256, 0, stream>>>(pw1, f1w0, f1w1, dw1, dw2, f2w1, bfW);
  k_mkT<<<CH, b256, 0, stream>>>(pw0, Tg);
  // img = X^T -> slotA ; padded leaky bf16 -> Ppad
  k_transpose_pad<<<dim3(CH / 32, NP / 32), b256, 0, stream>>>(X, slotA, Ppad);
  // ppm depthwise -> raw0 bf16 (bfH)
  k_dwconv17<<<dim3(9, CH), b256, 0, stream>>>(Ppad, Tg, bfH);
  k_stats_bf<<<CH, b256, 0, stream>>>(bfH, sum0, sq0);
  k_cvtT_bf<<<dim3(NP / 64, 8), b256, 0, stream>>>(bfH, bfB, sum0, sq0, pg0, pb0, CH);
  // ppm 1x1 -> raw1 bf16 (bfH; raw0 dead)
  k_mgemm256<<<NP / BN, b512, 0, stream>>>(bfW, bfB, nullptr, bfH, nullptr, nullptr, CH, 0);
  k_stats_bf<<<CH, b256, 0, stream>>>(bfH, sum1, sq1);
  // img2 = img + bn(raw1) -> slotD (Tg dead) ; bfB = leaky(img2)^T tiled
  k_fuse1<<<dim3(NP / 64, 8), b256, 0, stream>>>(slotA, bfH, sum1, sq1, pg1, pb1, slotD, bfB);
  // ffn1 conv0 -> raw2 bf16 (bfH)
  k_mgemm256<<<NP / BN, b512, 0, stream>>>(bfW + 65536, bfB, nullptr, bfH, nullptr, nullptr, CH, 0);
  k_stats_bf<<<CH, b256, 0, stream>>>(bfH, sum2, sq2);
  k_cvtT_bf<<<dim3(NP / 64, 8), b256, 0, stream>>>(bfH, bfB, sum2, sq2, f1g0, f1b0, CH);
  // ffn1 conv1 -> raw3 bf16 (bfH)
  k_mgemm256<<<NP / BN, b512, 0, stream>>>(bfW + 131072, bfB, nullptr, bfH, nullptr, nullptr, CH, 0);
  k_stats_bf<<<CH, b256, 0, stream>>>(bfH, sum3, sq3);
  // Xn = img2 + bn(raw3): fp32 NxC -> slotA ; bf16 NxC row -> bfB ; tiled -> bfBt
  k_fuse2<<<dim3(NP / 64, 8), b256, 0, stream>>>(slotD, bfH, sum3, sq3, f1g1, f1b1, slotA, bfB, bfBt);
  // dis: h -> bfH DIRECTLY in K-slab tiled bf16, bias+leaky, uint2 tiled stores
  k_mgemm256<<<NP / BN, b512, 0, stream>>>(bfW + 196608, bfBt, nullptr, nullptr, bfH, db1, CH, 1);
  k_mgemm<<<dim3(NP / 128, 3), b256, 0, stream>>>(bfW + 262144, bfH, sigT, nullptr, db2, CH, KSIG, 0, 12288);
  // edges
  k_edge<<<EDGES / 256, b256, 0, stream>>>(info, msk, sigT, aij, counts);
  k_scan1<<<NP / 256, b256, 0, stream>>>(counts, offsets, bsum);
  k_scan2<<<1, b256, 0, stream>>>(bsum, boff);
  k_scan3<<<NP / 256, b256, 0, stream>>>(offsets, boff, cursor);
  k_scatter<<<EDGES / 256, b256, 0, stream>>>(info, aij, cursor, srcs, aijw);
  // Xtr bf16 -> XtrBf (slotD; img2 dead)  [bfB row-major]
  k_agg<<<NP / 4, b256, 0, stream>>>(offsets, srcs, aijw, bfB, XtrBf);
  k_colstats<<<288, b256, 0, stream>>>(XtrBf, sumT, sqT);
  // img4 -> slotC (Ppad dead)
  k_mkimg4<<<dim3(CH / 32, NP / 32), b256, 0, stream>>>(slotA, XtrBf, sumT, sqT, bng, bnb, slotC);
  // ffn2 grouped 3x3 -> raw4bf (slotB+slotA; Xn fp32 dead)
  k_conv3x4<<<dim3(48, CH), b256, 0, stream>>>(slotC, f2w0, raw4bf);
  k_stats_bf<<<1024, b256, 0, stream>>>(raw4bf, sum4, sq4);
  k_cvtT_bf<<<dim3(NP / 64, 32), b256, 0, stream>>>(raw4bf, bfT1024, sum4, sq4, f2g0, f2b0, 1024);
  // ffn2 1x1 -> raw5 bf16 (slotB; raw4bf consumed)
  k_mgemm256<<<NP / BN, b512, 0, stream>>>(bfW + 360448, bfT1024, nullptr, raw5bf, nullptr, nullptr, 1024, 0);
  k_stats_bf<<<CH, b256, 0, stream>>>(raw5bf, sum5, sq5);
  k_final<<<dim3(NP / 32, CH / 32), b256, 0, stream>>>(raw5bf, slotC, sum5, sq5, f2g1, f2b1, out);
}

// Round 13
// 627.110 us; speedup vs baseline: 1.0427x; 1.0004x over previous
//
#include <hip/hip_runtime.h>
#include <cstddef>

#define HW 192
#define NP 36864          // H*W
#define CH 256
#define EDGES 294912
#define KSIG 289
#define SLOPE 0.01f
#define BNEPS 1e-5f
#define PADW 208          // padded image row (192 + 2*8)
#define PADSZ (PADW * PADW)   // 43264 u16 per channel
#define NP32 ((size_t)NP * 32)   // B-matrix K-slab stride (u16)
#define BN 144            // GEMM N-tile: NP/144 = 256 blocks = exactly 1/CU

typedef unsigned short u16;
typedef __attribute__((ext_vector_type(8))) short bf16x8;
typedef __attribute__((ext_vector_type(4))) float f32x4;

__device__ __forceinline__ float leaky(float x) { return x >= 0.f ? x : SLOPE * x; }
__device__ __forceinline__ u16 f2bf(float x) {
  unsigned u = __float_as_uint(x);
  unsigned r = (u + 0x7fffu + ((u >> 16) & 1u)) >> 16;
  return (u16)r;
}
__device__ __forceinline__ float bf2f(unsigned h) { return __uint_as_float(h << 16); }
__device__ __forceinline__ void bnss(const float* sums, const float* sqs,
                                     const float* g, const float* b, int k,
                                     float& s, float& h) {
  float mean = sums[k] * (1.f / NP);
  float var = sqs[k] * (1.f / NP) - mean * mean;
  s = g[k] * rsqrtf(var + BNEPS);
  h = b[k] - mean * s;
}

// async global->LDS DMA: wave-uniform LDS base, per-lane global addr (lane*16B)
__device__ __forceinline__ void gload_lds16(const u16* g, u16* l) {
  __builtin_amdgcn_global_load_lds(
      (const __attribute__((address_space(1))) void*)g,
      (__attribute__((address_space(3))) void*)l, 16, 0, 0);
}

// ---- img = X^T (fp32 CxN) + padded leaky bf16 image (borders pre-zeroed) ------
__global__ __launch_bounds__(256) void k_transpose_pad(const float* __restrict__ src,
                                                       float* __restrict__ dst,
                                                       u16* __restrict__ pad) {
  __shared__ float tile[32][33];
  int s0 = blockIdx.x * 32, r0 = blockIdx.y * 32;   // s0 = channel, r0 = node
  int tx = threadIdx.x & 31, ty = threadIdx.x >> 5;
#pragma unroll
  for (int j = 0; j < 4; j++)
    tile[ty + 8 * j][tx] = src[(size_t)(r0 + ty + 8 * j) * CH + s0 + tx];
  __syncthreads();
  int n = r0 + tx;
  int y = n / HW, x = n - y * HW;
#pragma unroll
  for (int j = 0; j < 4; j++) {
    int c = s0 + ty + 8 * j;
    float v = tile[tx][ty + 8 * j];
    dst[(size_t)c * NP + n] = v;
    pad[(size_t)c * PADSZ + (y + 8) * PADW + x + 8] = f2bf(leaky(v));
  }
}

// ---- global Toeplitz build: Tg[c][ky][n][k] = w[c][ky][k-n] (bf16) ------------
__global__ __launch_bounds__(256) void k_mkT(const float* __restrict__ w,
                                             u16* __restrict__ Tg) {
  int c = blockIdx.x;
  const float* wc = w + c * 289;
  u16* tc = Tg + (size_t)c * 8704;
  for (int i = threadIdx.x; i < 8704; i += 256) {
    int ky = i >> 9, rem = i & 511, n = rem >> 5, k = rem & 31;
    int kx = k - n;
    float v = (kx >= 0 && kx < 17) ? wc[ky * 17 + kx] : 0.f;
    tc[i] = f2bf(v);
  }
}

// ---- weight fp32 -> bf16, K-SLAB TILED per matrix: (r,k) -> (k/32, r, k%32) ---
__global__ __launch_bounds__(256) void k_cvtW(const float* __restrict__ pw1,
                                              const float* __restrict__ f1w0,
                                              const float* __restrict__ f1w1,
                                              const float* __restrict__ dw1,
                                              const float* __restrict__ dw2,
                                              const float* __restrict__ f2w1,
                                              u16* __restrict__ out) {
  int i = blockIdx.x * 256 + threadIdx.x;   // 0..622591
  float v;
  int off, j, R, Klog;
  if (i < 65536)       { off = 0;      j = i;          v = pw1[j];  R = 256; Klog = 8; }
  else if (i < 131072) { off = 65536;  j = i - 65536;  v = f1w0[j]; R = 256; Klog = 8; }
  else if (i < 196608) { off = 131072; j = i - 131072; v = f1w1[j]; R = 256; Klog = 8; }
  else if (i < 262144) { off = 196608; j = i - 196608; v = dw1[j];  R = 256; Klog = 8; }
  else if (i < 360448) { off = 262144; j = i - 262144;
                         v = (j < KSIG * 256) ? dw2[j] : 0.f;       R = 384; Klog = 8; }
  else                 { off = 360448; j = i - 360448; v = f2w1[j]; R = 256; Klog = 10; }
  int r = j >> Klog, k = j & ((1 << Klog) - 1);
  int ni = off + (k >> 5) * (R * 32) + r * 32 + (k & 31);
  out[ni] = f2bf(v);
}

// ---------------- per-row stats, bf16 input (one block per row) ----------------
__global__ __launch_bounds__(256) void k_stats_bf(const u16* __restrict__ Xr,
                                                  float* __restrict__ sums,
                                                  float* __restrict__ sqs) {
  int row = blockIdx.x;
  int t = threadIdx.x;
  const uint4* p = (const uint4*)(Xr + (size_t)row * NP);
  float s = 0.f, q = 0.f;
  for (int i = t; i < NP / 8; i += 256) {
    uint4 v = p[i];
    unsigned w[4] = {v.x, v.y, v.z, v.w};
#pragma unroll
    for (int j = 0; j < 4; j++) {
      float a = bf2f(w[j] & 0xffffu), c = bf2f(w[j] >> 16);
      s += a + c; q += a * a + c * c;
    }
  }
  __shared__ float ss[256], qq[256];
  ss[t] = s; qq[t] = q;
  __syncthreads();
  for (int d = 128; d > 0; d >>= 1) {
    if (t < d) { ss[t] += ss[t + d]; qq[t] += qq[t + d]; }
    __syncthreads();
  }
  if (t == 0) { sums[row] = ss[0]; sqs[row] = qq[0]; }
}

// ---- bf16 (M x NP) -> bf16 transposed K-SLAB tiled, leaky(bn(x)) inline -------
__global__ __launch_bounds__(256) void k_cvtT_bf(const u16* __restrict__ in,
                                                 u16* __restrict__ outT,
                                                 const float* __restrict__ sums,
                                                 const float* __restrict__ sqs,
                                                 const float* __restrict__ g,
                                                 const float* __restrict__ b, int M) {
  __shared__ float tile[32][65];
  int n0 = blockIdx.x * 64, k0 = blockIdx.y * 32;
  int t = threadIdx.x;
  int k = t >> 3, cg = (t & 7) * 8;
  float s, h; bnss(sums, sqs, g, b, k0 + k, s, h);
  uint4 v = *(const uint4*)&in[(size_t)(k0 + k) * NP + n0 + cg];
  unsigned w[4] = {v.x, v.y, v.z, v.w};
#pragma unroll
  for (int j = 0; j < 4; j++) {
    tile[k][cg + 2 * j]     = leaky(fmaf(bf2f(w[j] & 0xffffu), s, h));
    tile[k][cg + 2 * j + 1] = leaky(fmaf(bf2f(w[j] >> 16), s, h));
  }
  __syncthreads();
  int n = t >> 2, kg = (t & 3) * 8;
  uint4 o;
  o.x = (unsigned)f2bf(tile[kg + 0][n]) | ((unsigned)f2bf(tile[kg + 1][n]) << 16);
  o.y = (unsigned)f2bf(tile[kg + 2][n]) | ((unsigned)f2bf(tile[kg + 3][n]) << 16);
  o.z = (unsigned)f2bf(tile[kg + 4][n]) | ((unsigned)f2bf(tile[kg + 5][n]) << 16);
  o.w = (unsigned)f2bf(tile[kg + 6][n]) | ((unsigned)f2bf(tile[kg + 7][n]) << 16);
  *(uint4*)&outT[(size_t)(k0 >> 5) * NP32 + (size_t)(n0 + n) * 32 + kg] = o;
}

// ---- fuse1: img2 = img + bn(raw1); img2 fp32 (CxN) + leaky(img2)^T tiled ------
__global__ __launch_bounds__(256) void k_fuse1(const float* __restrict__ base,
                                               const u16* __restrict__ raw,
                                               const float* __restrict__ sums,
                                               const float* __restrict__ sqs,
                                               const float* __restrict__ g,
                                               const float* __restrict__ b,
                                               float* __restrict__ img2,
                                               u16* __restrict__ outT) {
  __shared__ float tile[32][65];
  int n0 = blockIdx.x * 64, k0 = blockIdx.y * 32;
  int t = threadIdx.x;
#pragma unroll
  for (int i = 0; i < 2; i++) {
    int ci = i * 256 + t;
    int k = ci >> 4, cg = (ci & 15) * 4;
    float s, h; bnss(sums, sqs, g, b, k0 + k, s, h);
    size_t idx = (size_t)(k0 + k) * NP + n0 + cg;
    float4 bv = *(const float4*)&base[idx];
    uint2 rv = *(const uint2*)&raw[idx];
    float r0 = bf2f(rv.x & 0xffffu), r1 = bf2f(rv.x >> 16);
    float r2 = bf2f(rv.y & 0xffffu), r3 = bf2f(rv.y >> 16);
    float4 o;
    o.x = bv.x + fmaf(r0, s, h); o.y = bv.y + fmaf(r1, s, h);
    o.z = bv.z + fmaf(r2, s, h); o.w = bv.w + fmaf(r3, s, h);
    *(float4*)&img2[idx] = o;
    tile[k][cg]     = leaky(o.x);
    tile[k][cg + 1] = leaky(o.y);
    tile[k][cg + 2] = leaky(o.z);
    tile[k][cg + 3] = leaky(o.w);
  }
  __syncthreads();
  int n = t >> 2, kg = (t & 3) * 8;
  uint4 o;
  o.x = (unsigned)f2bf(tile[kg + 0][n]) | ((unsigned)f2bf(tile[kg + 1][n]) << 16);
  o.y = (unsigned)f2bf(tile[kg + 2][n]) | ((unsigned)f2bf(tile[kg + 3][n]) << 16);
  o.z = (unsigned)f2bf(tile[kg + 4][n]) | ((unsigned)f2bf(tile[kg + 5][n]) << 16);
  o.w = (unsigned)f2bf(tile[kg + 6][n]) | ((unsigned)f2bf(tile[kg + 7][n]) << 16);
  *(uint4*)&outT[(size_t)(k0 >> 5) * NP32 + (size_t)(n0 + n) * 32 + kg] = o;
}

// ---- fuse2: Xn = img2 + bn(raw3); Xn fp32 NxC + Xn bf16 NxC (row) + tiled -----
__global__ __launch_bounds__(256) void k_fuse2(const float* __restrict__ base,
                                               const u16* __restrict__ raw,
                                               const float* __restrict__ sums,
                                               const float* __restrict__ sqs,
                                               const float* __restrict__ g,
                                               const float* __restrict__ b,
                                               float* __restrict__ XnT,
                                               u16* __restrict__ outT,
                                               u16* __restrict__ outTt) {
  __shared__ float tile[32][65];
  int n0 = blockIdx.x * 64, k0 = blockIdx.y * 32;
  int t = threadIdx.x;
#pragma unroll
  for (int i = 0; i < 2; i++) {
    int ci = i * 256 + t;
    int k = ci >> 4, cg = (ci & 15) * 4;
    float s, h; bnss(sums, sqs, g, b, k0 + k, s, h);
    size_t idx = (size_t)(k0 + k) * NP + n0 + cg;
    float4 bv = *(const float4*)&base[idx];
    uint2 rv = *(const uint2*)&raw[idx];
    float r0 = bf2f(rv.x & 0xffffu), r1 = bf2f(rv.x >> 16);
    float r2 = bf2f(rv.y & 0xffffu), r3 = bf2f(rv.y >> 16);
    tile[k][cg]     = bv.x + fmaf(r0, s, h);
    tile[k][cg + 1] = bv.y + fmaf(r1, s, h);
    tile[k][cg + 2] = bv.z + fmaf(r2, s, h);
    tile[k][cg + 3] = bv.w + fmaf(r3, s, h);
  }
  __syncthreads();
  int n = t >> 2, kg = (t & 3) * 8;
  float4 f0 = {tile[kg + 0][n], tile[kg + 1][n], tile[kg + 2][n], tile[kg + 3][n]};
  float4 f1 = {tile[kg + 4][n], tile[kg + 5][n], tile[kg + 6][n], tile[kg + 7][n]};
  *(float4*)&XnT[(size_t)(n0 + n) * CH + k0 + kg] = f0;
  *(float4*)&XnT[(size_t)(n0 + n) * CH + k0 + kg + 4] = f1;
  uint4 o;
  o.x = (unsigned)f2bf(f0.x) | ((unsigned)f2bf(f0.y) << 16);
  o.y = (unsigned)f2bf(f0.z) | ((unsigned)f2bf(f0.w) << 16);
  o.z = (unsigned)f2bf(f1.x) | ((unsigned)f2bf(f1.y) << 16);
  o.w = (unsigned)f2bf(f1.z) | ((unsigned)f2bf(f1.w) << 16);
  *(uint4*)&outT[(size_t)(n0 + n) * CH + k0 + kg] = o;                    // row (agg)
  *(uint4*)&outTt[(size_t)(k0 >> 5) * NP32 + (size_t)(n0 + n) * 32 + kg] = o; // tiled (GEMM)
}

// ---------------- MFMA GEMM (generic, M via blockIdx.y) ------------------------
// m97 structure: K-slab global + LINEAR stride-32 LDS + global_load_lds width=16.
__global__ __launch_bounds__(256) void k_mgemm(const u16* __restrict__ A,
                                               const u16* __restrict__ Bt,
                                               float* __restrict__ Outf,
                                               u16* __restrict__ Outb,
                                               const float* __restrict__ bias,
                                               int K, int Mstore, int actout,
                                               int aslab) {
  __shared__ u16 As[128 * 32];
  __shared__ u16 Bs[128 * 32];
  int t = threadIdx.x;
  int lane = t & 63, wave = t >> 6;
  int wm = (wave >> 1) * 64, wn = (wave & 1) * 64;
  int m0 = blockIdx.y * 128, n0 = blockIdx.x * 128;
  int r = lane & 15, q = lane >> 4;
  f32x4 acc[4][4];
#pragma unroll
  for (int a = 0; a < 4; a++)
#pragma unroll
    for (int b = 0; b < 4; b++) acc[a][b] = (f32x4){0.f, 0.f, 0.f, 0.f};

  int kiters = K >> 5;
  for (int ki = 0; ki < kiters; ki++) {
    const u16* Ag = A + (size_t)ki * aslab + (size_t)m0 * 32;
    const u16* Bg = Bt + (size_t)ki * NP32 + (size_t)n0 * 32;
#pragma unroll
    for (int j = 0; j < 4; j++) {
      int c = wave * 4 + j;          // 0..15, wave-uniform
      if (c < 8) gload_lds16(Ag + c * 512 + lane * 8, As + c * 512);
      else       gload_lds16(Bg + (c - 8) * 512 + lane * 8, Bs + (c - 8) * 512);
    }
    __syncthreads();                 // drains vmcnt -> LDS filled
    bf16x8 af[4], bfr[4];
#pragma unroll
    for (int mt = 0; mt < 4; mt++)
      af[mt] = *(const bf16x8*)&As[(wm + mt * 16 + r) * 32 + q * 8];
#pragma unroll
    for (int nt = 0; nt < 4; nt++)
      bfr[nt] = *(const bf16x8*)&Bs[(wn + nt * 16 + r) * 32 + q * 8];
#pragma unroll
    for (int mt = 0; mt < 4; mt++)
#pragma unroll
      for (int nt = 0; nt < 4; nt++)
        acc[mt][nt] = __builtin_amdgcn_mfma_f32_16x16x32_bf16(af[mt], bfr[nt], acc[mt][nt], 0, 0, 0);
    __syncthreads();                 // reads done before next overwrite
  }
#pragma unroll
  for (int mt = 0; mt < 4; mt++) {
    int mrow = m0 + wm + mt * 16 + q * 4;
#pragma unroll
    for (int i = 0; i < 4; i++) {
      int m = mrow + i;
      if (m >= Mstore) continue;
      float bs = bias ? bias[m] : 0.f;
#pragma unroll
      for (int nt = 0; nt < 4; nt++) {
        float v = acc[mt][nt][i] + bs;
        if (actout) v = leaky(v);
        size_t oi = (size_t)m * NP + n0 + wn + nt * 16 + r;
        if (Outb) Outb[oi] = f2bf(v); else Outf[oi] = v;
      }
    }
  }
}

// ---------------- MFMA GEMM, M=256, BN=144, DOUBLE-BUFFERED gload_lds ----------
// r12 showed per-block time (not tail) is the limiter: DMA issued then
// immediately barriered -> full ~900cy load latency exposed per K-step.
// Fix (guide's minimum 2-phase): issue tile ki+1's DMA into buf^1 BEFORE
// computing tile ki from buf; the end-of-step barrier drain then waits only
// (latency - compute_time). Same barrier orders buf reuse. LDS 2x25.6KB.
// Math order identical to r12 (bit-identical outputs).
__global__ __launch_bounds__(512) void k_mgemm256(const u16* __restrict__ A,
                                                  const u16* __restrict__ Bt,
                                                  float* __restrict__ Outf,
                                                  u16* __restrict__ Outb,
                                                  u16* __restrict__ OutbT,
                                                  const float* __restrict__ bias,
                                                  int K, int actout) {
  __shared__ u16 As[2][256 * 32];  // 2 x 16 KB
  __shared__ u16 Bs[2][BN * 32];   // 2 x 9 KB
  int t = threadIdx.x;
  int lane = t & 63, wave = t >> 6;
  int wm = wave * 32;              // 8 waves x 32 rows
  int n0 = blockIdx.x * BN;
  int r = lane & 15, q = lane >> 4;
  f32x4 acc[2][9];
#pragma unroll
  for (int a = 0; a < 2; a++)
#pragma unroll
    for (int b = 0; b < 9; b++) acc[a][b] = (f32x4){0.f, 0.f, 0.f, 0.f};

  int kiters = K >> 5;
  // prologue: stage tile 0 into buf 0
  {
    const u16* Bg = Bt + (size_t)n0 * 32;
#pragma unroll
    for (int j = 0; j < 4; j++) {
      int c = wave * 4 + j;          // 0..31, wave-uniform; 25 live chunks
      if (c < 16)      gload_lds16(A + c * 512 + lane * 8, As[0] + c * 512);
      else if (c < 25) gload_lds16(Bg + (c - 16) * 512 + lane * 8, Bs[0] + (c - 16) * 512);
    }
  }
  __syncthreads();
  int cur = 0;
  for (int ki = 0; ki < kiters; ki++) {
    // issue prefetch of tile ki+1 FIRST (latency hides under MFMA below)
    if (ki + 1 < kiters) {
      const u16* Ag = A + (size_t)(ki + 1) * 8192;
      const u16* Bg = Bt + (size_t)(ki + 1) * NP32 + (size_t)n0 * 32;
      int nxt = cur ^ 1;
#pragma unroll
      for (int j = 0; j < 4; j++) {
        int c = wave * 4 + j;
        if (c < 16)      gload_lds16(Ag + c * 512 + lane * 8, As[nxt] + c * 512);
        else if (c < 25) gload_lds16(Bg + (c - 16) * 512 + lane * 8, Bs[nxt] + (c - 16) * 512);
      }
    }
    // compute from buf[cur]
    bf16x8 bfr[9];
#pragma unroll
    for (int nt = 0; nt < 9; nt++)
      bfr[nt] = *(const bf16x8*)&Bs[cur][(nt * 16 + r) * 32 + q * 8];
#pragma unroll
    for (int mt = 0; mt < 2; mt++) {
      bf16x8 af = *(const bf16x8*)&As[cur][(wm + mt * 16 + r) * 32 + q * 8];
#pragma unroll
      for (int nt = 0; nt < 9; nt++)
        acc[mt][nt] = __builtin_amdgcn_mfma_f32_16x16x32_bf16(af, bfr[nt], acc[mt][nt], 0, 0, 0);
    }
    __syncthreads();   // drains vmcnt (prefetch had the compute phase to run)
    cur ^= 1;          // and orders buf reuse for the next prefetch
  }
#pragma unroll
  for (int mt = 0; mt < 2; mt++) {
    int mrow = wm + mt * 16 + q * 4;
    if (OutbT) {
      int slab = wave;                          // m>>5 == wave for all mt here
      int ko = mt * 16 + q * 4;                 // (m & 31) base for i=0
      float b0 = bias ? bias[mrow + 0] : 0.f;
      float b1 = bias ? bias[mrow + 1] : 0.f;
      float b2 = bias ? bias[mrow + 2] : 0.f;
      float b3 = bias ? bias[mrow + 3] : 0.f;
#pragma unroll
      for (int nt = 0; nt < 9; nt++) {
        int n = n0 + nt * 16 + r;
        float w0 = acc[mt][nt][0] + b0, w1 = acc[mt][nt][1] + b1;
        float w2 = acc[mt][nt][2] + b2, w3 = acc[mt][nt][3] + b3;
        if (actout) { w0 = leaky(w0); w1 = leaky(w1); w2 = leaky(w2); w3 = leaky(w3); }
        uint2 pk;
        pk.x = (unsigned)f2bf(w0) | ((unsigned)f2bf(w1) << 16);
        pk.y = (unsigned)f2bf(w2) | ((unsigned)f2bf(w3) << 16);
        *(uint2*)&OutbT[(size_t)slab * NP32 + (size_t)n * 32 + ko] = pk;
      }
      continue;
    }
#pragma unroll
    for (int i = 0; i < 4; i++) {
      int m = mrow + i;
      float bs = bias ? bias[m] : 0.f;
#pragma unroll
      for (int nt = 0; nt < 9; nt++) {
        float v = acc[mt][nt][i] + bs;
        if (actout) v = leaky(v);
        size_t oi = (size_t)m * NP + n0 + nt * 16 + r;
        if (Outb) Outb[oi] = f2bf(v); else Outf[oi] = v;
      }
    }
  }
}

// ---------------- depthwise 17x17 conv via MFMA, padded bf16 input -------------
__global__ __launch_bounds__(256) void k_dwconv17(const u16* __restrict__ pad,
                                                  const u16* __restrict__ Tg,
                                                  u16* __restrict__ outb) {
  int c = blockIdx.y;
  int tile = blockIdx.x;                  // 0..8
  int ty0 = (tile / 3) * 64, tx0 = (tile % 3) * 64;
  __shared__ u16 smIn[80 * 88];
  __shared__ u16 smT[17 * 16 * 40];
  const u16* pc = pad + (size_t)c * PADSZ;
  for (int cc = threadIdx.x; cc < 800; cc += 256) {
    int rr = cc / 10, j = cc - rr * 10;
    uint4 v = *(const uint4*)(pc + (ty0 + rr) * PADW + tx0 + j * 8);
    *(uint4*)(smIn + rr * 88 + j * 8) = v;
  }
  const u16* tc = Tg + (size_t)c * 8704;
  for (int cc = threadIdx.x; cc < 1088; cc += 256) {
    int rr = cc >> 2, j = cc & 3;
    uint4 v = *(const uint4*)(tc + rr * 32 + j * 8);
    *(uint4*)(smT + rr * 40 + j * 8) = v;
  }
  __syncthreads();
  int lane = threadIdx.x & 63, wave = threadIdx.x >> 6;
  int wy = wave * 16;
  int r = lane & 15, q = lane >> 4;
  f32x4 acc[4];
#pragma unroll
  for (int xt = 0; xt < 4; xt++) acc[xt] = (f32x4){0.f, 0.f, 0.f, 0.f};
#pragma unroll
  for (int ky = 0; ky < 17; ky++) {
    bf16x8 bfrag = *(const bf16x8*)&smT[(ky * 16 + r) * 40 + q * 8];
    int rowA = wy + r + ky;
#pragma unroll
    for (int xt = 0; xt < 4; xt++) {
      bf16x8 afrag = *(const bf16x8*)&smIn[rowA * 88 + xt * 16 + q * 8];
      acc[xt] = __builtin_amdgcn_mfma_f32_16x16x32_bf16(afrag, bfrag, acc[xt], 0, 0, 0);
    }
  }
  u16* oc = outb + (size_t)c * NP;
#pragma unroll
  for (int xt = 0; xt < 4; xt++) {
    int x = tx0 + xt * 16 + r;
#pragma unroll
    for (int i = 0; i < 4; i++) {
      int y = ty0 + wy + q * 4 + i;
      oc[y * HW + x] = f2bf(acc[xt][i]);
    }
  }
}

// ---------------- grouped 3x3 conv, row-sliding, no LDS, no barrier ------------
__global__ __launch_bounds__(256) void k_conv3x4(const float* __restrict__ in,
                                                 const float* __restrict__ w,
                                                 u16* __restrict__ out) {
  int wave = threadIdx.x >> 6, lane = threadIdx.x & 63;
  int c = blockIdx.y;
  int y = blockIdx.x * 4 + wave;
  const float* wc = w + (size_t)(4 * c) * 9;
  float wr[36];
#pragma unroll
  for (int k = 0; k < 36; k++) wr[k] = wc[k];
  float acc[4][3];
#pragma unroll
  for (int oc = 0; oc < 4; oc++)
#pragma unroll
    for (int s = 0; s < 3; s++) acc[oc][s] = 0.f;
  const float* base = in + (size_t)c * NP;
#pragma unroll
  for (int ky = 0; ky < 3; ky++) {
    int ry = y + ky - 1;
    if (ry < 0 || ry >= HW) continue;
    const float* rp = base + ry * HW;
    float a0 = leaky(rp[lane]);
    float a1 = leaky(rp[64 + lane]);
    float a2 = leaky(rp[128 + lane]);
    float e0 = __shfl(a0, 63), e1 = __shfl(a1, 63);
    float b1 = __shfl(a1, 0),  b2 = __shfl(a2, 0);
    float l0 = __shfl_up(a0, 1); if (lane == 0) l0 = 0.f;
    float l1 = __shfl_up(a1, 1); if (lane == 0) l1 = e0;
    float l2 = __shfl_up(a2, 1); if (lane == 0) l2 = e1;
    float r0 = __shfl_down(a0, 1); if (lane == 63) r0 = b1;
    float r1 = __shfl_down(a1, 1); if (lane == 63) r1 = b2;
    float r2 = __shfl_down(a2, 1); if (lane == 63) r2 = 0.f;
#pragma unroll
    for (int oc = 0; oc < 4; oc++) {
      float w0 = wr[oc * 9 + ky * 3], w1 = wr[oc * 9 + ky * 3 + 1], w2 = wr[oc * 9 + ky * 3 + 2];
      acc[oc][0] = fmaf(w0, l0, fmaf(w1, a0, fmaf(w2, r0, acc[oc][0])));
      acc[oc][1] = fmaf(w0, l1, fmaf(w1, a1, fmaf(w2, r1, acc[oc][1])));
      acc[oc][2] = fmaf(w0, l2, fmaf(w1, a2, fmaf(w2, r2, acc[oc][2])));
    }
  }
  size_t ob = (size_t)(4 * c) * NP + (size_t)y * HW + lane;
#pragma unroll
  for (int oc = 0; oc < 4; oc++) {
    out[ob + (size_t)oc * NP]       = f2bf(acc[oc][0]);
    out[ob + (size_t)oc * NP + 64]  = f2bf(acc[oc][1]);
    out[ob + (size_t)oc * NP + 128] = f2bf(acc[oc][2]);
  }
}

// ---------------- edge scores + dst histogram ----------------------------------
__global__ __launch_bounds__(256) void k_edge(const int* __restrict__ info,
                                              const float* __restrict__ msk,
                                              const float* __restrict__ sig,
                                              float* __restrict__ aij,
                                              int* __restrict__ counts) {
  int e = blockIdx.x * 256 + threadIdx.x;
  int4 ii = ((const int4*)info)[e];
  float s = sig[(size_t)ii.y * NP + ii.x] + sig[(size_t)ii.w * NP + ii.z];
  s = fminf(fmaxf(s, -5.f), 5.f);
  aij[e] = expf(s) * msk[e];
  atomicAdd(&counts[ii.z], 1);
}

// ---------------- counting-sort by dst -----------------------------------------
__global__ __launch_bounds__(256) void k_scan1(const int* __restrict__ counts,
                                               int* __restrict__ offsets,
                                               int* __restrict__ bsum) {
  __shared__ int sm[256];
  int t = threadIdx.x;
  int i = blockIdx.x * 256 + t;
  int v = counts[i];
  sm[t] = v;
  __syncthreads();
  for (int d = 1; d < 256; d <<= 1) {
    int add = (t >= d) ? sm[t - d] : 0;
    __syncthreads();
    sm[t] += add;
    __syncthreads();
  }
  offsets[i] = sm[t] - v;
  if (t == 255) bsum[blockIdx.x] = sm[255];
}
__global__ __launch_bounds__(256) void k_scan2(const int* __restrict__ bsum,
                                               int* __restrict__ boff) {
  __shared__ int sm[256];
  int t = threadIdx.x;
  int v = (t < 144) ? bsum[t] : 0;
  sm[t] = v;
  __syncthreads();
  for (int d = 1; d < 256; d <<= 1) {
    int add = (t >= d) ? sm[t - d] : 0;
    __syncthreads();
    sm[t] += add;
    __syncthreads();
  }
  boff[t] = sm[t] - v;
}
__global__ __launch_bounds__(256) void k_scan3(int* __restrict__ offsets,
                                               const int* __restrict__ boff,
                                               int* __restrict__ cursor) {
  int i = blockIdx.x * 256 + threadIdx.x;
  int o = offsets[i] + boff[blockIdx.x];
  offsets[i] = o;
  cursor[i] = o;
  if (i == 0) offsets[NP] = EDGES;
}
// scatter (src, aij) pre-sorted by dst
__global__ __launch_bounds__(256) void k_scatter(const int* __restrict__ info,
                                                 const float* __restrict__ aij,
                                                 int* __restrict__ cursor,
                                                 int* __restrict__ srcs,
                                                 float* __restrict__ aijw) {
  int e = blockIdx.x * 256 + threadIdx.x;
  int4 ii = ((const int4*)info)[e];
  int pos = atomicAdd(&cursor[ii.z], 1);
  srcs[pos] = ii.x;
  aijw[pos] = aij[e];
}

// ---------------- per-node aggregation: half-wave per edge stream --------------
__global__ __launch_bounds__(256) void k_agg(const int* __restrict__ offsets,
                                             const int* __restrict__ srcs,
                                             const float* __restrict__ aijw,
                                             const u16* __restrict__ XnBf,
                                             u16* __restrict__ XtrBf) {
  int wave = threadIdx.x >> 6, lane = threadIdx.x & 63;
  int node = blockIdx.x * 4 + wave;
  int o0 = offsets[node], o1 = offsets[node + 1];
  int half = lane >> 5, l32 = lane & 31;
  float acc[8] = {0.f, 0.f, 0.f, 0.f, 0.f, 0.f, 0.f, 0.f};
  float asum = 0.f;
  int i = o0 + half;
  for (; i + 2 < o1; i += 4) {
    int s0 = srcs[i], s1 = srcs[i + 2];
    float a0 = aijw[i], a1 = aijw[i + 2];
    uint4 v0 = ((const uint4*)(XnBf + (size_t)s0 * CH))[l32];
    uint4 v1 = ((const uint4*)(XnBf + (size_t)s1 * CH))[l32];
    unsigned w0[4] = {v0.x, v0.y, v0.z, v0.w};
    unsigned w1[4] = {v1.x, v1.y, v1.z, v1.w};
#pragma unroll
    for (int j = 0; j < 4; j++) {
      acc[2 * j]     = fmaf(a0, bf2f(w0[j] & 0xffffu), acc[2 * j]);
      acc[2 * j + 1] = fmaf(a0, bf2f(w0[j] >> 16),     acc[2 * j + 1]);
      acc[2 * j]     = fmaf(a1, bf2f(w1[j] & 0xffffu), acc[2 * j]);
      acc[2 * j + 1] = fmaf(a1, bf2f(w1[j] >> 16),     acc[2 * j + 1]);
    }
    asum += a0 + a1;
  }
  for (; i < o1; i += 2) {
    int s = srcs[i];
    float a = aijw[i];
    uint4 v = ((const uint4*)(XnBf + (size_t)s * CH))[l32];
    unsigned w[4] = {v.x, v.y, v.z, v.w};
#pragma unroll
    for (int j = 0; j < 4; j++) {
      acc[2 * j]     = fmaf(a, bf2f(w[j] & 0xffffu), acc[2 * j]);
      acc[2 * j + 1] = fmaf(a, bf2f(w[j] >> 16),     acc[2 * j + 1]);
    }
    asum += a;
  }
#pragma unroll
  for (int j = 0; j < 8; j++) acc[j] += __shfl_xor(acc[j], 32, 64);
  asum += __shfl_xor(asum, 32, 64);
  if (half == 0) {
    float inv = 1.f / (asum + 1e-5f);
    uint4 o;
    o.x = (unsigned)f2bf(acc[0] * inv) | ((unsigned)f2bf(acc[1] * inv) << 16);
    o.y = (unsigned)f2bf(acc[2] * inv) | ((unsigned)f2bf(acc[3] * inv) << 16);
    o.z = (unsigned)f2bf(acc[4] * inv) | ((unsigned)f2bf(acc[5] * inv) << 16);
    o.w = (unsigned)f2bf(acc[6] * inv) | ((unsigned)f2bf(acc[7] * inv) << 16);
    ((uint4*)(XtrBf + (size_t)node * CH))[l32] = o;
  }
}

// ---------------- bn1d stats (bf16 input) --------------------------------------
__global__ __launch_bounds__(256) void k_colstats(const u16* __restrict__ Xt,
                                                  float* __restrict__ sums,
                                                  float* __restrict__ sqs) {
  int c = threadIdx.x;
  float s = 0.f, q = 0.f;
  for (int n = blockIdx.x; n < NP; n += gridDim.x) {
    float v = bf2f(Xt[(size_t)n * CH + c]);
    s += v; q += v * v;
  }
  atomicAdd(&sums[c], s);
  atomicAdd(&sqs[c], q);
}

// ---------------- img4 = transpose(Xn + bn1d(Xtr bf16))  (N x C -> C x N) ------
__global__ __launch_bounds__(256) void k_mkimg4(const float* __restrict__ Xn,
                                                const u16* __restrict__ XtrBf,
                                                const float* __restrict__ sums,
                                                const float* __restrict__ sqs,
                                                const float* __restrict__ g,
                                                const float* __restrict__ b,
                                                float* __restrict__ img4) {
  __shared__ float tile[32][33];
  int c0 = blockIdx.x * 32, n0 = blockIdx.y * 32;
  int tx = threadIdx.x & 31, ty = threadIdx.x >> 5;
  int c = c0 + tx;
  float s, h; bnss(sums, sqs, g, b, c, s, h);
#pragma unroll
  for (int j = 0; j < 4; j++) {
    size_t idx = (size_t)(n0 + ty + 8 * j) * CH + c;
    tile[ty + 8 * j][tx] = Xn[idx] + fmaf(bf2f(XtrBf[idx]), s, h);
  }
  __syncthreads();
#pragma unroll
  for (int j = 0; j < 4; j++) {
    int cc = c0 + ty + 8 * j;
    img4[(size_t)cc * NP + n0 + tx] = tile[tx][ty + 8 * j];
  }
}

// ---------------- out(N x C) = transpose(bn(raw5 bf16) + img4) -----------------
__global__ __launch_bounds__(256) void k_final(const u16* __restrict__ raw5,
                                               const float* __restrict__ img4,
                                               const float* __restrict__ sums,
                                               const float* __restrict__ sqs,
                                               const float* __restrict__ g,
                                               const float* __restrict__ b,
                                               float* __restrict__ out) {
  __shared__ float tile[32][33];
  int n0 = blockIdx.x * 32, c0 = blockIdx.y * 32;
  int tx = threadIdx.x & 31, ty = threadIdx.x >> 5;
#pragma unroll
  for (int j = 0; j < 4; j++) {
    int c = c0 + ty + 8 * j;
    float s, h; bnss(sums, sqs, g, b, c, s, h);
    size_t idx = (size_t)c * NP + n0 + tx;
    tile[ty + 8 * j][tx] = fmaf(bf2f(raw5[idx]), s, h) + img4[idx];
  }
  __syncthreads();
#pragma unroll
  for (int j = 0; j < 4; j++) {
    int n = n0 + ty + 8 * j;
    out[(size_t)n * CH + c0 + tx] = tile[tx][ty + 8 * j];
  }
}

extern "C" void kernel_launch(void* const* d_in, const int* in_sizes, int n_in,
                              void* d_out, int out_size, void* d_ws, size_t ws_size,
                              hipStream_t stream) {
  (void)in_sizes; (void)n_in; (void)out_size; (void)ws_size;
  const float* X    = (const float*)d_in[0];
  const int*   info = (const int*)d_in[1];
  const float* msk  = (const float*)d_in[2];
  const float* pw0  = (const float*)d_in[3];
  const float* pg0  = (const float*)d_in[4];
  const float* pb0  = (const float*)d_in[5];
  const float* pw1  = (const float*)d_in[6];
  const float* pg1  = (const float*)d_in[7];
  const float* pb1  = (const float*)d_in[8];
  const float* f1w0 = (const float*)d_in[9];
  const float* f1g0 = (const float*)d_in[10];
  const float* f1b0 = (const float*)d_in[11];
  const float* f1w1 = (const float*)d_in[12];
  const float* f1g1 = (const float*)d_in[13];
  const float* f1b1 = (const float*)d_in[14];
  const float* dw1  = (const float*)d_in[15];
  const float* db1  = (const float*)d_in[16];
  const float* dw2  = (const float*)d_in[17];
  const float* db2  = (const float*)d_in[18];
  const float* bng  = (const float*)d_in[19];
  const float* bnb  = (const float*)d_in[20];
  const float* f2w0 = (const float*)d_in[21];
  const float* f2g0 = (const float*)d_in[22];
  const float* f2b0 = (const float*)d_in[23];
  const float* f2w1 = (const float*)d_in[24];
  const float* f2g1 = (const float*)d_in[25];
  const float* f2b1 = (const float*)d_in[26];
  float* out = (float*)d_out;

  float* ws = (float*)d_ws;
  float* sum0 = ws + 0;    float* sq0 = ws + 256;
  float* sum1 = ws + 512;  float* sq1 = ws + 768;
  float* sum2 = ws + 1024; float* sq2 = ws + 1280;
  float* sum3 = ws + 1536; float* sq3 = ws + 1792;
  float* sum5 = ws + 2048; float* sq5 = ws + 2304;
  float* sumT = ws + 2560; float* sqT = ws + 2816;   // atomic targets, zeroed
  float* sum4 = ws + 3072; float* sq4 = ws + 4096;   // 1024 each
  int* counts  = (int*)(ws + 8192);
  int* offsets = (int*)(ws + 45056);
  int* cursor  = (int*)(ws + 82176);
  int* bsum    = (int*)(ws + 119296);
  int* boff    = (int*)(ws + 119552);
  int* srcs    = (int*)(ws + 131072);      // EDGES
  float* aij   = ws + 425984;              // EDGES (unsorted)
  const size_t S = (size_t)NP * CH;        // 9437184 words
  float* slotD = ws + 720896;
  float* slotB = slotD + S;
  float* slotA = slotB + S;
  float* slotC = slotA + S;
  u16* bfB  = (u16*)(slotC + S);           // NP x 256 bf16
  u16* bfH  = bfB + S;                     // raw0/raw1/raw2/raw3/h-bf16
  float* sigT = (float*)(bfH + S);         // KSIG x NP fp32
  u16* bfW  = (u16*)(sigT + (size_t)KSIG * NP);
  float* aijw = (float*)(bfW + 622592);    // EDGES, sorted by dst
  // early-phase aliases into dead fp32 slots:
  u16* Ppad = (u16*)slotC;                 // 256ch x 208x208 bf16 padded leaky img
  u16* Tg   = (u16*)slotD;                 // 256 x 8704 Toeplitz
  u16* raw4bf  = (u16*)slotB;              // 1024 x NP bf16, spans slotB+slotA
  u16* bfT1024 = bfB;                      // NP x 1024 bf16 (K-slab tiled)
  u16* XtrBf   = (u16*)slotD;              // N x C bf16 (img2/Tg dead)
  u16* raw5bf  = (u16*)slotB;              // C x NP bf16 (raw4bf dead after cvtT_bf)
  u16* bfBt    = (u16*)sigT;               // NP x 256 bf16 K-slab tiled (dis GEMM B);
                                           // dead before k_mgemm writes sigT

  hipMemsetAsync(ws, 0, 5120 * sizeof(float), stream);
  hipMemsetAsync(counts, 0, NP * sizeof(int), stream);
  hipMemsetAsync(Ppad, 0, (size_t)PADSZ * CH * sizeof(u16), stream);

  dim3 b256(256), b512(512);
  k_cvtW<<<2432, b256, 0, stream>>>(pw1, f1w0, f1w1, dw1, dw2, f2w1, bfW);
  k_mkT<<<CH, b256, 0, stream>>>(pw0, Tg);
  // img = X^T -> slotA ; padded leaky bf16 -> Ppad
  k_transpose_pad<<<dim3(CH / 32, NP / 32), b256, 0, stream>>>(X, slotA, Ppad);
  // ppm depthwise -> raw0 bf16 (bfH)
  k_dwconv17<<<dim3(9, CH), b256, 0, stream>>>(Ppad, Tg, bfH);
  k_stats_bf<<<CH, b256, 0, stream>>>(bfH, sum0, sq0);
  k_cvtT_bf<<<dim3(NP / 64, 8), b256, 0, stream>>>(bfH, bfB, sum0, sq0, pg0, pb0, CH);
  // ppm 1x1 -> raw1 bf16 (bfH; raw0 dead)
  k_mgemm256<<<NP / BN, b512, 0, stream>>>(bfW, bfB, nullptr, bfH, nullptr, nullptr, CH, 0);
  k_stats_bf<<<CH, b256, 0, stream>>>(bfH, sum1, sq1);
  // img2 = img + bn(raw1) -> slotD (Tg dead) ; bfB = leaky(img2)^T tiled
  k_fuse1<<<dim3(NP / 64, 8), b256, 0, stream>>>(slotA, bfH, sum1, sq1, pg1, pb1, slotD, bfB);
  // ffn1 conv0 -> raw2 bf16 (bfH)
  k_mgemm256<<<NP / BN, b512, 0, stream>>>(bfW + 65536, bfB, nullptr, bfH, nullptr, nullptr, CH, 0);
  k_stats_bf<<<CH, b256, 0, stream>>>(bfH, sum2, sq2);
  k_cvtT_bf<<<dim3(NP / 64, 8), b256, 0, stream>>>(bfH, bfB, sum2, sq2, f1g0, f1b0, CH);
  // ffn1 conv1 -> raw3 bf16 (bfH)
  k_mgemm256<<<NP / BN, b512, 0, stream>>>(bfW + 131072, bfB, nullptr, bfH, nullptr, nullptr, CH, 0);
  k_stats_bf<<<CH, b256, 0, stream>>>(bfH, sum3, sq3);
  // Xn = img2 + bn(raw3): fp32 NxC -> slotA ; bf16 NxC row -> bfB ; tiled -> bfBt
  k_fuse2<<<dim3(NP / 64, 8), b256, 0, stream>>>(slotD, bfH, sum3, sq3, f1g1, f1b1, slotA, bfB, bfBt);
  // dis: h -> bfH DIRECTLY in K-slab tiled bf16, bias+leaky, uint2 tiled stores
  k_mgemm256<<<NP / BN, b512, 0, stream>>>(bfW + 196608, bfBt, nullptr, nullptr, bfH, db1, CH, 1);
  k_mgemm<<<dim3(NP / 128, 3), b256, 0, stream>>>(bfW + 262144, bfH, sigT, nullptr, db2, CH, KSIG, 0, 12288);
  // edges
  k_edge<<<EDGES / 256, b256, 0, stream>>>(info, msk, sigT, aij, counts);
  k_scan1<<<NP / 256, b256, 0, stream>>>(counts, offsets, bsum);
  k_scan2<<<1, b256, 0, stream>>>(bsum, boff);
  k_scan3<<<NP / 256, b256, 0, stream>>>(offsets, boff, cursor);
  k_scatter<<<EDGES / 256, b256, 0, stream>>>(info, aij, cursor, srcs, aijw);
  // Xtr bf16 -> XtrBf (slotD; img2 dead)  [bfB row-major]
  k_agg<<<NP / 4, b256, 0, stream>>>(offsets, srcs, aijw, bfB, XtrBf);
  k_colstats<<<288, b256, 0, stream>>>(XtrBf, sumT, sqT);
  // img4 -> slotC (Ppad dead)
  k_mkimg4<<<dim3(CH / 32, NP / 32), b256, 0, stream>>>(slotA, XtrBf, sumT, sqT, bng, bnb, slotC);
  // ffn2 grouped 3x3 -> raw4bf (slotB+slotA; Xn fp32 dead)
  k_conv3x4<<<dim3(48, CH), b256, 0, stream>>>(slotC, f2w0, raw4bf);
  k_stats_bf<<<1024, b256, 0, stream>>>(raw4bf, sum4, sq4);
  k_cvtT_bf<<<dim3(NP / 64, 32), b256, 0, stream>>>(raw4bf, bfT1024, sum4, sq4, f2g0, f2b0, 1024);
  // ffn2 1x1 -> raw5 bf16 (slotB; raw4bf consumed)
  k_mgemm256<<<NP / BN, b512, 0, stream>>>(bfW + 360448, bfT1024, nullptr, raw5bf, nullptr, nullptr, 1024, 0);
  k_stats_bf<<<CH, b256, 0, stream>>>(raw5bf, sum5, sq5);
  k_final<<<dim3(NP / 32, CH / 32), b256, 0, stream>>>(raw5bf, slotC, sum5, sq5, f2g1, f2b1, out);
}